// Round 23
// baseline (446.616 us; speedup 1.0000x reference)
//
#include <hip/hip_runtime.h>
#include <hip/hip_bf16.h>
#include <math.h>

constexpr int NB = 8, NS = 1024, ND = 1024, NIN = 256, NPROC = 512, KIN = 128, KPROC = 256;

typedef __attribute__((ext_vector_type(8))) short bf16x8;
typedef __attribute__((ext_vector_type(4))) float f32x4;

#define VMCNT(n) asm volatile("s_waitcnt vmcnt(" #n ")" ::: "memory")
#define LGKMCNT(n) asm volatile("s_waitcnt lgkmcnt(" #n ")" ::: "memory")

__device__ inline float gelu_f(float x) {
    return 0.5f * x * (1.0f + erff(x * 0.7071067811865476f));
}
__device__ inline unsigned short f2b(float f) {
    __hip_bfloat16 h = __float2bfloat16(f);
    return *reinterpret_cast<unsigned short*>(&h);
}
__device__ inline float b2f(unsigned short u) {
    unsigned int v = (unsigned int)u << 16;
    return __uint_as_float(v);
}
__device__ inline void gload16(const void* g, void* l) {
    __builtin_amdgcn_global_load_lds(
        (const __attribute__((address_space(1))) void*)g,
        (__attribute__((address_space(3))) void*)l, 16, 0, 0);
}

// ---------------------------------------------------------------------------
// Fused f32->bf16 conversions + biascat init.
// ---------------------------------------------------------------------------
__global__ __launch_bounds__(256)
void cvt_all_kernel(const float* __restrict__ x, const float* __restrict__ rin,
                    const float* __restrict__ rout, const float* __restrict__ affw,
                    const float* __restrict__ patt, const float* __restrict__ iin,
                    const float* __restrict__ iout, const float* __restrict__ aff_b,
                    unsigned short* __restrict__ xb, unsigned short* __restrict__ rinb,
                    unsigned short* __restrict__ routb, unsigned short* __restrict__ affbw,
                    unsigned short* __restrict__ pattb, unsigned short* __restrict__ iinb,
                    unsigned short* __restrict__ ioutb, float* __restrict__ biascat)
{
    if (blockIdx.x == 0) {
        int t = threadIdx.x;
        biascat[t] = aff_b[t];
        biascat[256 + t] = 0.f;
    }
    long gi = (long)blockIdx.x * 256 + threadIdx.x;
    long stride = (long)gridDim.x * 256;
    for (; gi < 3342336; gi += stride) {
        const float4* s; ushort4* d; long off;
        if (gi < 2097152)      { s = (const float4*)x;    d = (ushort4*)xb;    off = gi; }
        else if (gi < 2883584) { s = (const float4*)rin;  d = (ushort4*)rinb;  off = gi - 2097152; }
        else if (gi < 3145728) { s = (const float4*)rout; d = (ushort4*)routb; off = gi - 2883584; }
        else if (gi < 3211264) { s = (const float4*)affw; d = (ushort4*)affbw; off = gi - 3145728; }
        else if (gi < 3276800) { s = (const float4*)patt; d = (ushort4*)pattb; off = gi - 3211264; }
        else if (gi < 3325952) { s = (const float4*)iin;  d = (ushort4*)iinb;  off = gi - 3276800; }
        else                   { s = (const float4*)iout; d = (ushort4*)ioutb; off = gi - 3325952; }
        float4 v = s[off];
        ushort4 o;
        o.x = f2b(v.x); o.y = f2b(v.y); o.z = f2b(v.z); o.w = f2b(v.w);
        d[off] = o;
    }
}

// ---------------------------------------------------------------------------
// 128x128 bf16 MFMA GEMM, BK=32 triple-buffer, one barrier/tile, 4 waves,
// counted vmcnt + 2-bit XOR swizzle + XCD grid swizzle. 48KB LDS.
// ---------------------------------------------------------------------------
__global__ __launch_bounds__(256)
void gemm128s(const unsigned short* __restrict__ A, int lda,
              const unsigned short* __restrict__ B, int ldb,
              const float* __restrict__ bias,
              unsigned short* __restrict__ C16, int ldc,
              int K, int nbx)
{
    __shared__ __align__(16) unsigned short Ab[3][128 * 32];
    __shared__ __align__(16) unsigned short Bb[3][128 * 32];
    int o = blockIdx.x;
    int cpx = gridDim.x >> 3;
    int swz = (o & 7) * cpx + (o >> 3);
    int by = swz / nbx, bx = swz - by * nbx;
    int row0 = by * 128, col0 = bx * 128;

    int t = threadIdx.x;
    int w = t >> 6, l = t & 63, l15 = l & 15, g = l >> 4;
    int wr = w >> 1, wc = w & 1;
    int NT = K >> 5;

    f32x4 acc[4][4];
#pragma unroll
    for (int i = 0; i < 4; ++i)
#pragma unroll
        for (int j = 0; j < 4; ++j) acc[i][j] = (f32x4){0.f, 0.f, 0.f, 0.f};

    auto STAGE = [&](int c, int kt) {
        int k0 = kt * 32;
#pragma unroll
        for (int i = 0; i < 2; ++i) {
            int gi = t + i * 256;
            int row = gi >> 2, cg = gi & 3;
            int cgs = cg ^ ((row >> 1) & 3);
            gload16(&A[(long)(row0 + row) * lda + k0 + cgs * 8], &Ab[c][gi * 8]);
        }
#pragma unroll
        for (int i = 0; i < 2; ++i) {
            int gi = t + i * 256;
            int row = gi >> 2, cg = gi & 3;
            int cgs = cg ^ ((row >> 1) & 3);
            gload16(&B[(long)(col0 + row) * ldb + k0 + cgs * 8], &Bb[c][gi * 8]);
        }
    };

    STAGE(0, 0);
    STAGE(1, 1);

    int cbr = (g ^ ((l15 >> 1) & 3)) * 16;

    int cur = 0;
    for (int T = 0; T < NT; ++T) {
        if (T + 1 < NT) { VMCNT(4); } else { VMCNT(0); }
        __builtin_amdgcn_s_barrier();
        asm volatile("" ::: "memory");

        const char* Ab_ = (const char*)&Ab[cur][0];
        const char* Bb_ = (const char*)&Bb[cur][0];
        bf16x8 af[4], bfr[4];
#pragma unroll
        for (int mi = 0; mi < 4; ++mi)
            af[mi] = *(const bf16x8*)(Ab_ + (wr * 64 + mi * 16 + l15) * 64 + cbr);
#pragma unroll
        for (int ni = 0; ni < 4; ++ni)
            bfr[ni] = *(const bf16x8*)(Bb_ + (wc * 64 + ni * 16 + l15) * 64 + cbr);

        if (T + 2 < NT) {
            int nxt = cur + 2;
            if (nxt >= 3) nxt -= 3;
            STAGE(nxt, T + 2);
        }

        LGKMCNT(0);
        __builtin_amdgcn_sched_barrier(0);
        __builtin_amdgcn_s_setprio(1);
#pragma unroll
        for (int mi = 0; mi < 4; ++mi)
#pragma unroll
            for (int ni = 0; ni < 4; ++ni)
                acc[mi][ni] = __builtin_amdgcn_mfma_f32_16x16x32_bf16(
                    af[mi], bfr[ni], acc[mi][ni], 0, 0, 0);
        __builtin_amdgcn_s_setprio(0);

        cur = (cur == 2) ? 0 : cur + 1;
    }

#pragma unroll
    for (int mi = 0; mi < 4; ++mi) {
#pragma unroll
        for (int ni = 0; ni < 4; ++ni) {
            int col = col0 + wc * 64 + ni * 16 + l15;
            float bv = bias ? bias[col] : 0.f;
#pragma unroll
            for (int r = 0; r < 4; ++r) {
                int row = row0 + wr * 64 + mi * 16 + g * 4 + r;
                float v = acc[mi][ni][r] + bv;
                float vp = __shfl_xor(v, 1);
                if (!(l15 & 1)) {
                    unsigned int u = (unsigned int)f2b(v) | ((unsigned int)f2b(vp) << 16);
                    *(unsigned int*)&C16[(long)row * ldc + col] = u;
                }
            }
        }
    }
}

// ---------------------------------------------------------------------------
// 128x64 N-tile variant: same pipeline, gate vmcnt(3), 36KB LDS.
// ---------------------------------------------------------------------------
__global__ __launch_bounds__(256)
void gemm128x64(const unsigned short* __restrict__ A, int lda,
                const unsigned short* __restrict__ B, int ldb,
                const float* __restrict__ bias,
                unsigned short* __restrict__ C16, int ldc,
                int K, int nbx)
{
    __shared__ __align__(16) unsigned short Ab[3][128 * 32];
    __shared__ __align__(16) unsigned short Bb[3][64 * 32];
    int o = blockIdx.x;
    int cpx = gridDim.x >> 3;
    int swz = (o & 7) * cpx + (o >> 3);
    int by = swz / nbx, bx = swz - by * nbx;
    int row0 = by * 128, col0 = bx * 64;

    int t = threadIdx.x;
    int w = t >> 6, l = t & 63, l15 = l & 15, g = l >> 4;
    int wr = w >> 1, wc = w & 1;
    int NT = K >> 5;

    f32x4 acc[4][2];
#pragma unroll
    for (int i = 0; i < 4; ++i)
#pragma unroll
        for (int j = 0; j < 2; ++j) acc[i][j] = (f32x4){0.f, 0.f, 0.f, 0.f};

    auto STAGE = [&](int c, int kt) {
        int k0 = kt * 32;
#pragma unroll
        for (int i = 0; i < 2; ++i) {
            int gi = t + i * 256;
            int row = gi >> 2, cg = gi & 3;
            int cgs = cg ^ ((row >> 1) & 3);
            gload16(&A[(long)(row0 + row) * lda + k0 + cgs * 8], &Ab[c][gi * 8]);
        }
        {
            int gi = t;
            int row = gi >> 2, cg = gi & 3;
            int cgs = cg ^ ((row >> 1) & 3);
            gload16(&B[(long)(col0 + row) * ldb + k0 + cgs * 8], &Bb[c][gi * 8]);
        }
    };

    STAGE(0, 0);
    STAGE(1, 1);

    int cbr = (g ^ ((l15 >> 1) & 3)) * 16;

    int cur = 0;
    for (int T = 0; T < NT; ++T) {
        if (T + 1 < NT) { VMCNT(3); } else { VMCNT(0); }
        __builtin_amdgcn_s_barrier();
        asm volatile("" ::: "memory");

        const char* Ab_ = (const char*)&Ab[cur][0];
        const char* Bb_ = (const char*)&Bb[cur][0];
        bf16x8 af[4], bfr[2];
#pragma unroll
        for (int mi = 0; mi < 4; ++mi)
            af[mi] = *(const bf16x8*)(Ab_ + (wr * 64 + mi * 16 + l15) * 64 + cbr);
#pragma unroll
        for (int ni = 0; ni < 2; ++ni)
            bfr[ni] = *(const bf16x8*)(Bb_ + (wc * 32 + ni * 16 + l15) * 64 + cbr);

        if (T + 2 < NT) {
            int nxt = cur + 2;
            if (nxt >= 3) nxt -= 3;
            STAGE(nxt, T + 2);
        }

        LGKMCNT(0);
        __builtin_amdgcn_sched_barrier(0);
        __builtin_amdgcn_s_setprio(1);
#pragma unroll
        for (int mi = 0; mi < 4; ++mi)
#pragma unroll
            for (int ni = 0; ni < 2; ++ni)
                acc[mi][ni] = __builtin_amdgcn_mfma_f32_16x16x32_bf16(
                    af[mi], bfr[ni], acc[mi][ni], 0, 0, 0);
        __builtin_amdgcn_s_setprio(0);

        cur = (cur == 2) ? 0 : cur + 1;
    }

#pragma unroll
    for (int mi = 0; mi < 4; ++mi) {
#pragma unroll
        for (int ni = 0; ni < 2; ++ni) {
            int col = col0 + wc * 32 + ni * 16 + l15;
            float bv = bias ? bias[col] : 0.f;
#pragma unroll
            for (int r = 0; r < 4; ++r) {
                int row = row0 + wr * 64 + mi * 16 + g * 4 + r;
                float v = acc[mi][ni][r] + bv;
                float vp = __shfl_xor(v, 1);
                if (!(l15 & 1)) {
                    unsigned int u = (unsigned int)f2b(v) | ((unsigned int)f2b(vp) << 16);
                    *(unsigned int*)&C16[(long)row * ldc + col] = u;
                }
            }
        }
    }
}

// ---------------------------------------------------------------------------
// gemm128e: 128x64 triple-buffer pipeline + full epilogue + batch (z).
// act: 0 plain (+resid opt), 1 gelu, 2 split@256.
// ---------------------------------------------------------------------------
__global__ __launch_bounds__(256)
void gemm128e(const unsigned short* __restrict__ A, long sA, int lda,
              const unsigned short* __restrict__ B, long sB, int ldb,
              const float* __restrict__ bias,
              const float* __restrict__ resid, long sR, int ldr,
              float* __restrict__ C32, long sC32, int ldc32,
              unsigned short* __restrict__ C16, long sC16, int ldc16,
              float* __restrict__ C32b, int ldc32b,
              int K, int nbx, int act)
{
    __shared__ __align__(16) unsigned short Ab[3][128 * 32];
    __shared__ __align__(16) unsigned short Bb[3][64 * 32];
    int bz = blockIdx.z;
    const unsigned short* Abase = A + (long)bz * sA;
    const unsigned short* Bbase = B + (long)bz * sB;
    int o = blockIdx.x;
    int cpx = gridDim.x >> 3;
    int swz = (o & 7) * cpx + (o >> 3);
    int by = swz / nbx, bx = swz - by * nbx;
    int row0 = by * 128, col0 = bx * 64;

    int t = threadIdx.x;
    int w = t >> 6, l = t & 63, l15 = l & 15, g = l >> 4;
    int wr = w >> 1, wc = w & 1;
    int NT = K >> 5;

    f32x4 acc[4][2];
#pragma unroll
    for (int i = 0; i < 4; ++i)
#pragma unroll
        for (int j = 0; j < 2; ++j) acc[i][j] = (f32x4){0.f, 0.f, 0.f, 0.f};

    auto STAGE = [&](int c, int kt) {
        int k0 = kt * 32;
#pragma unroll
        for (int i = 0; i < 2; ++i) {
            int gi = t + i * 256;
            int row = gi >> 2, cg = gi & 3;
            int cgs = cg ^ ((row >> 1) & 3);
            gload16(&Abase[(long)(row0 + row) * lda + k0 + cgs * 8], &Ab[c][gi * 8]);
        }
        {
            int gi = t;
            int row = gi >> 2, cg = gi & 3;
            int cgs = cg ^ ((row >> 1) & 3);
            gload16(&Bbase[(long)(col0 + row) * ldb + k0 + cgs * 8], &Bb[c][gi * 8]);
        }
    };

    STAGE(0, 0);
    STAGE(1, 1);

    int cbr = (g ^ ((l15 >> 1) & 3)) * 16;

    int cur = 0;
    for (int T = 0; T < NT; ++T) {
        if (T + 1 < NT) { VMCNT(3); } else { VMCNT(0); }
        __builtin_amdgcn_s_barrier();
        asm volatile("" ::: "memory");

        const char* Ab_ = (const char*)&Ab[cur][0];
        const char* Bb_ = (const char*)&Bb[cur][0];
        bf16x8 af[4], bfr[2];
#pragma unroll
        for (int mi = 0; mi < 4; ++mi)
            af[mi] = *(const bf16x8*)(Ab_ + (wr * 64 + mi * 16 + l15) * 64 + cbr);
#pragma unroll
        for (int ni = 0; ni < 2; ++ni)
            bfr[ni] = *(const bf16x8*)(Bb_ + (wc * 32 + ni * 16 + l15) * 64 + cbr);

        if (T + 2 < NT) {
            int nxt = cur + 2;
            if (nxt >= 3) nxt -= 3;
            STAGE(nxt, T + 2);
        }

        LGKMCNT(0);
        __builtin_amdgcn_sched_barrier(0);
        __builtin_amdgcn_s_setprio(1);
#pragma unroll
        for (int mi = 0; mi < 4; ++mi)
#pragma unroll
            for (int ni = 0; ni < 2; ++ni)
                acc[mi][ni] = __builtin_amdgcn_mfma_f32_16x16x32_bf16(
                    af[mi], bfr[ni], acc[mi][ni], 0, 0, 0);
        __builtin_amdgcn_s_setprio(0);

        cur = (cur == 2) ? 0 : cur + 1;
    }

#pragma unroll
    for (int mi = 0; mi < 4; ++mi) {
#pragma unroll
        for (int ni = 0; ni < 2; ++ni) {
            int col = col0 + wc * 32 + ni * 16 + l15;
            float bv = bias ? bias[col] : 0.f;
#pragma unroll
            for (int r = 0; r < 4; ++r) {
                int row = row0 + wr * 64 + mi * 16 + g * 4 + r;
                float v = acc[mi][ni][r] + bv;
                if (act == 2) {
                    if (col < 256) {
                        C32[(long)row * ldc32 + col] = v;
                    } else {
                        v = gelu_f(v);
                        C32b[(long)row * ldc32b + (col - 256)] = v;
                        C16[(long)row * ldc16 + (col - 256)] = f2b(v);
                    }
                    continue;
                }
                if (act == 1) v = gelu_f(v);
                if (resid) v += resid[(long)bz * sR + (long)row * ldr + col];
                if (C32) C32[(long)bz * sC32 + (long)row * ldc32 + col] = v;
                if (C16) C16[(long)bz * sC16 + (long)row * ldc16 + col] = f2b(v);
            }
        }
    }
}

// ---------------------------------------------------------------------------
// Flash attention v4: 4 waves x 16 q-rows (q-tile 64), kv-tile 32.
// K double-buffered LDS via global_load_lds (counted vmcnt, XOR swizzle);
// V reg-staged. 31KB LDS (D=128) -> 4 blocks/CU; grid 16x8x8 = 1024.
// ---------------------------------------------------------------------------
template <int D>
__global__ __launch_bounds__(256)
void attn_mfma(unsigned short* __restrict__ qkv, int stride, int koff, int voff, float scale)
{
    constexpr int KVB = 32;
    constexpr int GRL = D / 8;                 // granules per row
    constexpr int NITK = (KVB * GRL) / 256;    // 2 for D=128, 1 for D=64
    constexpr int NITV = NITK;
    constexpr int NKS = D / 32;
    constexpr int NF = D / 16;
    constexpr int LV = 40;                     // Vt pitch (kc dim 32 + 8)
    constexpr int LP = 40;                     // Ps pitch
    constexpr int NT = NS / KVB;               // 32 kv-tiles

    __shared__ __align__(16) unsigned short Ks[2][KVB * D];
    __shared__ __align__(16) unsigned short Vt[D * LV];
    __shared__ __align__(16) unsigned short Ps[64 * LP];

    int b = blockIdx.z, h = blockIdx.y, qt = blockIdx.x;
    int t = threadIdx.x, w = t >> 6, l = t & 63, l15 = l & 15, g = l >> 4;
    int wq = w * 16;
    long qbase = ((long)b * NS + qt * 64) * stride + h * D;
    long kvbase = (long)b * NS * stride + h * D;

    // Q fragments: 16 q-rows per wave
    bf16x8 qreg[NKS];
#pragma unroll
    for (int ks = 0; ks < NKS; ++ks)
        qreg[ks] = *(const bf16x8*)&qkv[qbase + (long)(wq + l15) * stride + g * 8 + ks * 32];

    auto KSTAGE = [&](int c, int kt) {
#pragma unroll
        for (int i = 0; i < NITK; ++i) {
            int gi = t + i * 256;
            int row = gi / GRL, cg = gi % GRL;
            int cgs = cg ^ (row & 7);
            gload16(&qkv[kvbase + (long)(kt * KVB + row) * stride + koff + cgs * 8],
                    &Ks[c][gi * 8]);
        }
    };
    uint4 vp[NITV];
    auto VLOAD = [&](int kt) {
#pragma unroll
        for (int i = 0; i < NITV; ++i) {
            int vgi = t + i * 256;
            int kc = vgi & (KVB - 1), db = vgi / KVB;
            vp[i] = *(const uint4*)&qkv[kvbase + (long)(kt * KVB + kc) * stride + voff + db * 8];
        }
    };
    auto VWRITE = [&]() {
#pragma unroll
        for (int i = 0; i < NITV; ++i) {
            int vgi = t + i * 256;
            int kc = vgi & (KVB - 1), db = vgi / KVB;
            uint4 v = vp[i];
            Vt[(db * 8 + 0) * LV + kc] = (unsigned short)(v.x & 0xffff);
            Vt[(db * 8 + 1) * LV + kc] = (unsigned short)(v.x >> 16);
            Vt[(db * 8 + 2) * LV + kc] = (unsigned short)(v.y & 0xffff);
            Vt[(db * 8 + 3) * LV + kc] = (unsigned short)(v.y >> 16);
            Vt[(db * 8 + 4) * LV + kc] = (unsigned short)(v.z & 0xffff);
            Vt[(db * 8 + 5) * LV + kc] = (unsigned short)(v.z >> 16);
            Vt[(db * 8 + 6) * LV + kc] = (unsigned short)(v.w & 0xffff);
            Vt[(db * 8 + 7) * LV + kc] = (unsigned short)(v.w >> 16);
        }
    };

    // prologue: K0, V0, K1 in flight; drain K0+V0; fill Vt; barrier
    KSTAGE(0, 0);
    VLOAD(0);
    KSTAGE(1, 1);
    if constexpr (NITK == 2) { VMCNT(2); } else { VMCNT(1); }
    VWRITE();
    LGKMCNT(0);
    __builtin_amdgcn_sched_barrier(0);
    __builtin_amdgcn_s_barrier();

    float m_run = -INFINITY, l_run = 0.f;
    f32x4 zero4 = {0.f, 0.f, 0.f, 0.f};
    f32x4 oacc[NF];
#pragma unroll
    for (int nf = 0; nf < NF; ++nf) oacc[nf] = zero4;

    int xr = (l15 & 7) << 4;
    for (int kt = 0; kt < NT; ++kt) {
        if (kt + 1 < NT) VLOAD(kt + 1);

        // QK^T: St[kc][q] over 32 kc rows (2 fragments)
        const char* ksb = (const char*)&Ks[kt & 1][0];
        f32x4 st[2];
#pragma unroll
        for (int f = 0; f < 2; ++f) st[f] = zero4;
#pragma unroll
        for (int ks = 0; ks < NKS; ++ks) {
#pragma unroll
            for (int f = 0; f < 2; ++f) {
                int cb = (g * 16 + ks * 64) ^ xr;
                bf16x8 a = *(const bf16x8*)(ksb + (f * 16 + l15) * (D * 2) + cb);
                st[f] = __builtin_amdgcn_mfma_f32_16x16x32_bf16(a, qreg[ks], st[f], 0, 0, 0);
            }
        }
        // online softmax (q col = l15; lanes l15, +16, +32, +48 share col)
        float pm = -INFINITY;
#pragma unroll
        for (int f = 0; f < 2; ++f) {
            st[f] *= scale;
#pragma unroll
            for (int r = 0; r < 4; ++r) pm = fmaxf(pm, st[f][r]);
        }
        pm = fmaxf(pm, __shfl_xor(pm, 16));
        pm = fmaxf(pm, __shfl_xor(pm, 32));
        float mn = fmaxf(m_run, pm);
        float corr = __expf(m_run - mn);
        float rs = 0.f;
#pragma unroll
        for (int f = 0; f < 2; ++f) {
            float p0 = __expf(st[f][0] - mn);
            float p1 = __expf(st[f][1] - mn);
            float p2 = __expf(st[f][2] - mn);
            float p3 = __expf(st[f][3] - mn);
            rs += (p0 + p1) + (p2 + p3);
            ushort4 pw;
            pw.x = f2b(p0); pw.y = f2b(p1); pw.z = f2b(p2); pw.w = f2b(p3);
            *(ushort4*)&Ps[(wq + l15) * LP + f * 16 + g * 4] = pw;
        }
        rs += __shfl_xor(rs, 16);
        rs += __shfl_xor(rs, 32);
        l_run = l_run * corr + rs;
        m_run = mn;
        float corrO[4];
#pragma unroll
        for (int r = 0; r < 4; ++r) corrO[r] = __shfl(corr, g * 4 + r);
#pragma unroll
        for (int nf = 0; nf < NF; ++nf)
#pragma unroll
            for (int r = 0; r < 4; ++r) oacc[nf][r] *= corrO[r];

        // PV: contraction over 32 kc (single K-slot)
#pragma unroll
        for (int nf = 0; nf < NF; ++nf) {
            bf16x8 vb = *(const bf16x8*)&Vt[(nf * 16 + l15) * LV + g * 8];
            bf16x8 pa = *(const bf16x8*)&Ps[(wq + l15) * LP + g * 8];
            oacc[nf] = __builtin_amdgcn_mfma_f32_16x16x32_bf16(pa, vb, oacc[nf], 0, 0, 0);
        }

        if (kt + 1 < NT) {
            LGKMCNT(0);
            __builtin_amdgcn_sched_barrier(0);
            __builtin_amdgcn_s_barrier();       // A: all Ks/Vt/Ps reads done
            if (kt + 2 < NT) {
                KSTAGE(kt & 1, kt + 2);
                if constexpr (NITK == 2) { VMCNT(2); } else { VMCNT(1); }
            } else {
                VMCNT(0);
            }
            VWRITE();                            // Vt <- V(kt+1)
            LGKMCNT(0);
            __builtin_amdgcn_sched_barrier(0);
            __builtin_amdgcn_s_barrier();       // B: tile kt+1 visible
        }
    }

    // epilogue
    float lo[4];
#pragma unroll
    for (int r = 0; r < 4; ++r) lo[r] = __shfl(l_run, g * 4 + r);
#pragma unroll
    for (int nf = 0; nf < NF; ++nf)
#pragma unroll
        for (int r = 0; r < 4; ++r) {
            float o = oacc[nf][r] / lo[r];
            qkv[qbase + (long)(wq + g * 4 + r) * stride + nf * 16 + l15] = f2b(o);
        }
}

// ---------------------------------------------------------------------------
__global__ __launch_bounds__(256)
void maxpart_aff_kernel(const float* __restrict__ aff, float* __restrict__ part)
{
    int sc = blockIdx.x, b = blockIdx.y, t = threadIdx.x;
    float m = -INFINITY;
    for (int s = sc * 32; s < (sc + 1) * 32; ++s)
        m = fmaxf(m, aff[((long)b * NS + s) * NIN + t]);
    part[(b * 32 + sc) * NIN + t] = m;
}

__global__ __launch_bounds__(256)
void rank_input_kernel(const float* __restrict__ part, int* __restrict__ idx_out,
                       float* __restrict__ w_out)
{
    int b = blockIdx.x, t = threadIdx.x;
    __shared__ float lg[256], rv[256];
    float m = part[(b * 32) * NIN + t];
#pragma unroll
    for (int sc = 1; sc < 32; ++sc) m = fmaxf(m, part[(b * 32 + sc) * NIN + t]);
    float l = m * 0.5f;
    lg[t] = l;
    rv[t] = l;
    __syncthreads();
    for (int off = 128; off; off >>= 1) {
        if (t < off) rv[t] = fmaxf(rv[t], rv[t + off]);
        __syncthreads();
    }
    float mx = rv[0];
    __syncthreads();
    float e = expf(l - mx);
    rv[t] = e;
    __syncthreads();
    for (int off = 128; off; off >>= 1) {
        if (t < off) rv[t] += rv[t + off];
        __syncthreads();
    }
    float Zs = rv[0];
    float soft = e / Zs;
    __syncthreads();
    int rank = 0;
    for (int j = 0; j < 256; ++j) {
        float vj = lg[j];
        rank += (vj > l) || (vj == l && j < t);
    }
    rv[t] = (rank < KIN) ? soft : 0.f;
    __syncthreads();
    for (int off = 128; off; off >>= 1) {
        if (t < off) rv[t] += rv[t + off];
        __syncthreads();
    }
    float msum = rv[0];
    if (rank < KIN) {
        idx_out[b * KIN + rank] = t;
        w_out[b * KIN + rank] = soft / (msum + 1e-8f);
    }
}

__global__ __launch_bounds__(512)
void rank_proc_kernel(const float* __restrict__ finals, int* __restrict__ pidx)
{
    int b = blockIdx.x, t = threadIdx.x;
    __shared__ float v[512];
    float xv = finals[b * NPROC + t];
    v[t] = xv;
    __syncthreads();
    int rank = 0;
    for (int j = 0; j < 512; ++j) {
        float vj = v[j];
        rank += (vj > xv) || (vj == xv && j < t);
    }
    if (rank < KPROC) pidx[b * KPROC + rank] = t;
}

// ---------------------------------------------------------------------------
// LN + routed gather, wave-per-row. Block = 4 waves = 4 rows; grid = 2048.
// ---------------------------------------------------------------------------
__global__ __launch_bounds__(256)
void ln_gather_kernel(const float* __restrict__ a, const unsigned short* __restrict__ bsrc,
                      const float* __restrict__ gg, const float* __restrict__ be,
                      const int* __restrict__ idx_in, const float* __restrict__ w_sel,
                      unsigned short* __restrict__ sel_acts)
{
    int w = threadIdx.x >> 6, l = threadIdx.x & 63;
    long row = (long)blockIdx.x * 4 + w;
    int b = (int)(row >> 10);
    __shared__ float lnv[4][256];

    float4 av = *(const float4*)&a[row * 256 + l * 4];
    ushort4 bu = *(const ushort4*)&bsrc[row * 256 + l * 4];
    float v0 = av.x + b2f(bu.x);
    float v1 = av.y + b2f(bu.y);
    float v2 = av.z + b2f(bu.z);
    float v3 = av.w + b2f(bu.w);
    float s = (v0 + v1) + (v2 + v3);
#pragma unroll
    for (int off = 1; off < 64; off <<= 1) s += __shfl_xor(s, off);
    float mean = s * (1.f / 256.f);
    float d0 = v0 - mean, d1 = v1 - mean, d2 = v2 - mean, d3 = v3 - mean;
    float ss = (d0 * d0 + d1 * d1) + (d2 * d2 + d3 * d3);
#pragma unroll
    for (int off = 1; off < 64; off <<= 1) ss += __shfl_xor(ss, off);
    float rstd = rsqrtf(ss * (1.f / 256.f) + 1e-5f);
    float4 gv = *(const float4*)&gg[l * 4];
    float4 bev = *(const float4*)&be[l * 4];
    lnv[w][l * 4 + 0] = d0 * rstd * gv.x + bev.x;
    lnv[w][l * 4 + 1] = d1 * rstd * gv.y + bev.y;
    lnv[w][l * 4 + 2] = d2 * rstd * gv.z + bev.z;
    lnv[w][l * 4 + 3] = d3 * rstd * gv.w + bev.w;
    int id0 = idx_in[b * KIN + l];
    int id1 = idx_in[b * KIN + l + 64];
    sel_acts[row * KIN + l] = f2b(lnv[w][id0] * w_sel[b * KIN + l]);
    sel_acts[row * KIN + l + 64] = f2b(lnv[w][id1] * w_sel[b * KIN + l + 64]);
}

__global__ void gather_sel_cw_b(const float* __restrict__ comb_w, const int* __restrict__ idx_in,
                                unsigned short* __restrict__ sel_cw)
{
    int gidx = blockIdx.x * 256 + threadIdx.x;
    int b = gidx >> 16;
    int rem = gidx & 65535;
    int pb = rem >> 7, j = rem & 127;
    sel_cw[gidx] = f2b(comb_w[pb * NIN + idx_in[b * KIN + j]]);
}

__global__ void gather_sel_proc_b(const unsigned short* __restrict__ proc_acts,
                                  const int* __restrict__ pidx,
                                  unsigned short* __restrict__ sel_proc)
{
    int s = blockIdx.x, b = blockIdx.y, j = threadIdx.x;
    long row = (long)b * NS + s;
    sel_proc[row * KPROC + j] = proc_acts[row * NPROC + pidx[b * KPROC + j]];
}

__global__ void gather_sel_projT(const float* __restrict__ out_proj_w, const int* __restrict__ pidx,
                                 unsigned short* __restrict__ selT)
{
    int gidx = blockIdx.x * 256 + threadIdx.x;
    int b = gidx >> 15;
    int rem = gidx & 32767;
    int d = rem >> 5;
    int kp0 = (rem & 31) * 8;
    unsigned int u[4];
#pragma unroll
    for (int i = 0; i < 4; ++i) {
        unsigned short e0 = f2b(out_proj_w[(long)pidx[b * KPROC + kp0 + 2 * i] * ND + d]);
        unsigned short e1 = f2b(out_proj_w[(long)pidx[b * KPROC + kp0 + 2 * i + 1] * ND + d]);
        u[i] = (unsigned int)e0 | ((unsigned int)e1 << 16);
    }
    uint4 o; o.x = u[0]; o.y = u[1]; o.z = u[2]; o.w = u[3];
    *(uint4*)&selT[((long)b * ND + d) * KPROC + kp0] = o;
}

__global__ __launch_bounds__(512)
void maxpart_kernel(const unsigned short* __restrict__ proc, float* __restrict__ part)
{
    int sc = blockIdx.x, b = blockIdx.y, t = threadIdx.x;
    float m = -INFINITY;
    for (int s = sc * 32; s < (sc + 1) * 32; ++s)
        m = fmaxf(m, b2f(proc[((long)b * NS + s) * NPROC + t]));
    part[(b * 32 + sc) * NPROC + t] = m;
}

// ---------------------------------------------------------------------------
// relevance split: rel1 then finals (wave-per-p, coalesced a2)
// ---------------------------------------------------------------------------
__global__ __launch_bounds__(512)
void rel1_kernel(const int* __restrict__ idx_in, const float* __restrict__ a1w,
                 const float* __restrict__ a1b, float* __restrict__ rel1g)
{
    int b = blockIdx.x, t = threadIdx.x;
    __shared__ int sidx[KIN];
    if (t < KIN) sidx[t] = idx_in[b * KIN + t];
    __syncthreads();
    float r1 = a1b[t];
    const float* a1row = a1w + (long)t * NIN;
    for (int j = 0; j < KIN; ++j) r1 += a1row[sidx[j]];
    rel1g[b * 512 + t] = gelu_f(r1);
}

__global__ __launch_bounds__(256)
void finals_kernel(const float* __restrict__ maxpart, const float* __restrict__ rel1g,
                   const float* __restrict__ a2w, const float* __restrict__ a2b,
                   float* __restrict__ finals)
{
    int b = blockIdx.y;
    int w = threadIdx.x >> 6, l = threadIdx.x & 63;
    __shared__ float r1[512];
    for (int i = threadIdx.x; i < 512; i += 256) r1[i] = rel1g[b * 512 + i];
    __syncthreads();
#pragma unroll 1
    for (int pi = 0; pi < 16; ++pi) {
        int p = blockIdx.x * 64 + w * 16 + pi;
        const float* a2row = a2w + (long)p * 512;
        float acc = 0.f;
#pragma unroll
        for (int i = 0; i < 8; ++i)
            acc += a2row[l + i * 64] * r1[l + i * 64];
#pragma unroll
        for (int off = 1; off < 64; off <<= 1) acc += __shfl_xor(acc, off);
        float m = (l < 32) ? maxpart[((long)b * 32 + l) * NPROC + p] : -INFINITY;
#pragma unroll
        for (int off = 1; off < 32; off <<= 1) m = fmaxf(m, __shfl_xor(m, off));
        if (l == 0) {
            float r = acc + a2b[p];
            float sig = 1.f / (1.f + expf(-r));
            finals[b * NPROC + p] = m * sig;
        }
    }
}

// ---------------------------------------------------------------------------
extern "C" void kernel_launch(void* const* d_in, const int* in_sizes, int n_in,
                              void* d_out, int out_size, void* d_ws, size_t ws_size,
                              hipStream_t stream)
{
    const float* x       = (const float*)d_in[0];
    const float* r_in_w  = (const float*)d_in[1];
    const float* r_in_b  = (const float*)d_in[2];
    const float* r_out_w = (const float*)d_in[3];
    const float* r_out_b = (const float*)d_in[4];
    const float* aff_w   = (const float*)d_in[5];
    const float* aff_b   = (const float*)d_in[6];
    const float* patterns= (const float*)d_in[7];
    const float* i_in_w  = (const float*)d_in[8];
    const float* i_in_b  = (const float*)d_in[9];
    const float* i_out_w = (const float*)d_in[10];
    const float* i_out_b = (const float*)d_in[11];
    const float* ln_g    = (const float*)d_in[12];
    const float* ln_b    = (const float*)d_in[13];
    const float* comb_w  = (const float*)d_in[14];
    const float* out_proj_w = (const float*)d_in[15];
    const float* a1w     = (const float*)d_in[16];
    const float* a1b     = (const float*)d_in[17];
    const float* a2w     = (const float*)d_in[18];
    const float* a2b     = (const float*)d_in[19];
    float* out = (float*)d_out;

    char* ws = (char*)d_ws;
    unsigned short* qkv1b    = (unsigned short*)(ws + 0);
    unsigned short* contextb = (unsigned short*)(ws + 50331648);
    unsigned short* xb       = (unsigned short*)(ws + 67108864);
    unsigned short* w_rin_b  = (unsigned short*)(ws + 83886080);
    unsigned short* w_rout_b = (unsigned short*)(ws + 90177536);
    unsigned short* w_aff_b  = (unsigned short*)(ws + 92274688);
    unsigned short* patt_b   = (unsigned short*)(ws + 92798976);
    unsigned short* w_iin_b  = (unsigned short*)(ws + 93323264);
    unsigned short* w_iout_b = (unsigned short*)(ws + 93716480);
    float* w_sel   = (float*)(ws + 93855744);
    int*   idx_in  = (int*)(ws + 93859840);
    float* finals  = (float*)(ws + 93863936);
    int*   pidx    = (int*)(ws + 93880320);
    float* affin   = (float*)(ws + 94019584);
    float* acts0   = (float*)(ws + 102408192);
    unsigned short* acts0b = (unsigned short*)(ws + 110796800);
    unsigned short* qkv2b  = (unsigned short*)(ws + 114991104);
    unsigned short* attn2projb = (unsigned short*)(ws + 0);
    unsigned short* proc_actsb = (unsigned short*)(ws + 16777216);
    unsigned short* sel_actsb = (unsigned short*)(ws + 33554432);
    unsigned short* sel_cwb   = (unsigned short*)(ws + 35651584);
    unsigned short* sel_procb = (unsigned short*)(ws + 36700160);
    unsigned short* sel_projT = (unsigned short*)(ws + 40894464);
    float* biascat  = (float*)(ws + 45088768);
    float* part_aff = (float*)(ws + 45091840);
    float* maxpart  = (float*)(ws + 45353984);
    float* rel1g    = (float*)(ws + 45878272);

    // 0. all conversions + biascat init in one launch
    cvt_all_kernel<<<2048, 256, 0, stream>>>(
        x, r_in_w, r_out_w, aff_w, patterns, i_in_w, i_out_w, aff_b,
        xb, w_rin_b, w_rout_b, w_aff_b, patt_b, w_iin_b, w_iout_b, biascat);

    // 1. qkv1 = x @ r_in_w^T + b (1536 blocks)
    gemm128s<<<1536, 256, 0, stream>>>(xb, ND, w_rin_b, ND, r_in_b, qkv1b, 3 * ND, ND, 24);
    // 2. MHA-1 (q-tile 64, kv-tile 32: 1024 blocks = 4/CU)
    attn_mfma<128><<<dim3(16, 8, 8), 256, 0, stream>>>(qkv1b, 3 * ND, ND, 2 * ND, 0.088388347648318447f);
    // 3. context (128x64 tile, 1024 blocks)
    gemm128x64<<<1024, 256, 0, stream>>>(qkv1b, 3 * ND, w_rout_b, ND, r_out_b, contextb, ND, ND, 16);
    // 4. fused affinity+patterns (split epilogue, 512 blocks)
    gemm128e<<<dim3(512, 1, 1), 256, 0, stream>>>(
        contextb, 0, ND, w_aff_b, 0, ND, biascat, nullptr, 0, 0,
        affin, 0, NIN, acts0b, 0, NIN, acts0, NIN, ND, 8, 2);
    // 5. routing
    maxpart_aff_kernel<<<dim3(32, NB), 256, 0, stream>>>(affin, part_aff);
    rank_input_kernel<<<NB, 256, 0, stream>>>(part_aff, idx_in, w_sel);
    // 6. qkv2 (768 blocks)
    gemm128x64<<<768, 256, 0, stream>>>(acts0b, NIN, w_iin_b, NIN, i_in_b, qkv2b, 3 * NIN, NIN, 12);
    // 7. MHA-2 (q-tile 64, kv-tile 32: 512 blocks)
    attn_mfma<64><<<dim3(16, 4, 8), 256, 0, stream>>>(qkv2b, 3 * NIN, NIN, 2 * NIN, 0.125f);
    // 8. attn2 out-proj -> bf16 (256 blocks)
    gemm128e<<<dim3(256, 1, 1), 256, 0, stream>>>(
        qkv2b, 0, 3 * NIN, w_iout_b, 0, NIN, i_out_b, nullptr, 0, 0,
        nullptr, 0, 0, attn2projb, 0, NIN, nullptr, 0, NIN, 4, 0);
    // 9. LN + routed gather (wave-per-row, 2048 blocks)
    ln_gather_kernel<<<2048, 256, 0, stream>>>(acts0, attn2projb, ln_g, ln_b,
                                               idx_in, w_sel, sel_actsb);
    gather_sel_cw_b<<<2048, 256, 0, stream>>>(comb_w, idx_in, sel_cwb);
    // 10. proc_acts -> bf16 (batched, 64 x 8)
    gemm128e<<<dim3(64, 1, NB), 256, 0, stream>>>(
        sel_actsb, (long)NS * KIN, KIN, sel_cwb, (long)NPROC * KIN, KIN,
        nullptr, nullptr, 0, 0,
        nullptr, 0, 0, proc_actsb, (long)NS * NPROC, NPROC, nullptr, 0, KIN, 8, 1);
    // 11. final scores + top-256
    maxpart_kernel<<<dim3(32, NB), 512, 0, stream>>>(proc_actsb, maxpart);
    rel1_kernel<<<NB, 512, 0, stream>>>(idx_in, a1w, a1b, rel1g);
    finals_kernel<<<dim3(8, NB), 256, 0, stream>>>(maxpart, rel1g, a2w, a2b, finals);
    rank_proc_kernel<<<NB, 512, 0, stream>>>(finals, pidx);
    // 12. output gathers + GEMM + residual (batched, 128 x 8)
    gather_sel_proc_b<<<dim3(NS, NB), KPROC, 0, stream>>>(proc_actsb, pidx, sel_procb);
    gather_sel_projT<<<1024, 256, 0, stream>>>(out_proj_w, pidx, sel_projT);
    gemm128e<<<dim3(128, 1, NB), 256, 0, stream>>>(
        sel_procb, (long)NS * KPROC, KPROC, sel_projT, (long)ND * KPROC, KPROC,
        nullptr, x, (long)NS * ND, ND,
        out, (long)NS * ND, ND, nullptr, 0, 0, nullptr, 0, KPROC, 16, 0);
    (void)in_sizes; (void)n_in; (void)out_size; (void)ws_size;
}

// Round 24
// 405.866 us; speedup vs baseline: 1.1004x; 1.1004x over previous
//
#include <hip/hip_runtime.h>
#include <hip/hip_bf16.h>
#include <math.h>

constexpr int NB = 8, NS = 1024, ND = 1024, NIN = 256, NPROC = 512, KIN = 128, KPROC = 256;

typedef __attribute__((ext_vector_type(8))) short bf16x8;
typedef __attribute__((ext_vector_type(4))) float f32x4;

#define VMCNT(n) asm volatile("s_waitcnt vmcnt(" #n ")" ::: "memory")
#define LGKMCNT(n) asm volatile("s_waitcnt lgkmcnt(" #n ")" ::: "memory")

__device__ inline float gelu_f(float x) {
    return 0.5f * x * (1.0f + erff(x * 0.7071067811865476f));
}
__device__ inline unsigned short f2b(float f) {
    __hip_bfloat16 h = __float2bfloat16(f);
    return *reinterpret_cast<unsigned short*>(&h);
}
__device__ inline float b2f(unsigned short u) {
    unsigned int v = (unsigned int)u << 16;
    return __uint_as_float(v);
}
__device__ inline void gload16(const void* g, void* l) {
    __builtin_amdgcn_global_load_lds(
        (const __attribute__((address_space(1))) void*)g,
        (__attribute__((address_space(3))) void*)l, 16, 0, 0);
}

// ---------------------------------------------------------------------------
// Fused f32->bf16 conversions + biascat init.
// ---------------------------------------------------------------------------
__global__ __launch_bounds__(256)
void cvt_all_kernel(const float* __restrict__ x, const float* __restrict__ rin,
                    const float* __restrict__ rout, const float* __restrict__ affw,
                    const float* __restrict__ patt, const float* __restrict__ iin,
                    const float* __restrict__ iout, const float* __restrict__ aff_b,
                    unsigned short* __restrict__ xb, unsigned short* __restrict__ rinb,
                    unsigned short* __restrict__ routb, unsigned short* __restrict__ affbw,
                    unsigned short* __restrict__ pattb, unsigned short* __restrict__ iinb,
                    unsigned short* __restrict__ ioutb, float* __restrict__ biascat)
{
    if (blockIdx.x == 0) {
        int t = threadIdx.x;
        biascat[t] = aff_b[t];
        biascat[256 + t] = 0.f;
    }
    long gi = (long)blockIdx.x * 256 + threadIdx.x;
    long stride = (long)gridDim.x * 256;
    for (; gi < 3342336; gi += stride) {
        const float4* s; ushort4* d; long off;
        if (gi < 2097152)      { s = (const float4*)x;    d = (ushort4*)xb;    off = gi; }
        else if (gi < 2883584) { s = (const float4*)rin;  d = (ushort4*)rinb;  off = gi - 2097152; }
        else if (gi < 3145728) { s = (const float4*)rout; d = (ushort4*)routb; off = gi - 2883584; }
        else if (gi < 3211264) { s = (const float4*)affw; d = (ushort4*)affbw; off = gi - 3145728; }
        else if (gi < 3276800) { s = (const float4*)patt; d = (ushort4*)pattb; off = gi - 3211264; }
        else if (gi < 3325952) { s = (const float4*)iin;  d = (ushort4*)iinb;  off = gi - 3276800; }
        else                   { s = (const float4*)iout; d = (ushort4*)ioutb; off = gi - 3325952; }
        float4 v = s[off];
        ushort4 o;
        o.x = f2b(v.x); o.y = f2b(v.y); o.z = f2b(v.z); o.w = f2b(v.w);
        d[off] = o;
    }
}

// ---------------------------------------------------------------------------
// 128x128 bf16 MFMA GEMM, BK=32 triple-buffer, one barrier/tile, 4 waves,
// counted vmcnt + 2-bit XOR swizzle + XCD grid swizzle. 48KB LDS.
// ---------------------------------------------------------------------------
__global__ __launch_bounds__(256)
void gemm128s(const unsigned short* __restrict__ A, int lda,
              const unsigned short* __restrict__ B, int ldb,
              const float* __restrict__ bias,
              unsigned short* __restrict__ C16, int ldc,
              int K, int nbx)
{
    __shared__ __align__(16) unsigned short Ab[3][128 * 32];
    __shared__ __align__(16) unsigned short Bb[3][128 * 32];
    int o = blockIdx.x;
    int cpx = gridDim.x >> 3;
    int swz = (o & 7) * cpx + (o >> 3);
    int by = swz / nbx, bx = swz - by * nbx;
    int row0 = by * 128, col0 = bx * 128;

    int t = threadIdx.x;
    int w = t >> 6, l = t & 63, l15 = l & 15, g = l >> 4;
    int wr = w >> 1, wc = w & 1;
    int NT = K >> 5;

    f32x4 acc[4][4];
#pragma unroll
    for (int i = 0; i < 4; ++i)
#pragma unroll
        for (int j = 0; j < 4; ++j) acc[i][j] = (f32x4){0.f, 0.f, 0.f, 0.f};

    auto STAGE = [&](int c, int kt) {
        int k0 = kt * 32;
#pragma unroll
        for (int i = 0; i < 2; ++i) {
            int gi = t + i * 256;
            int row = gi >> 2, cg = gi & 3;
            int cgs = cg ^ ((row >> 1) & 3);
            gload16(&A[(long)(row0 + row) * lda + k0 + cgs * 8], &Ab[c][gi * 8]);
        }
#pragma unroll
        for (int i = 0; i < 2; ++i) {
            int gi = t + i * 256;
            int row = gi >> 2, cg = gi & 3;
            int cgs = cg ^ ((row >> 1) & 3);
            gload16(&B[(long)(col0 + row) * ldb + k0 + cgs * 8], &Bb[c][gi * 8]);
        }
    };

    STAGE(0, 0);
    STAGE(1, 1);

    int cbr = (g ^ ((l15 >> 1) & 3)) * 16;

    int cur = 0;
    for (int T = 0; T < NT; ++T) {
        if (T + 1 < NT) { VMCNT(4); } else { VMCNT(0); }
        __builtin_amdgcn_s_barrier();
        asm volatile("" ::: "memory");

        const char* Ab_ = (const char*)&Ab[cur][0];
        const char* Bb_ = (const char*)&Bb[cur][0];
        bf16x8 af[4], bfr[4];
#pragma unroll
        for (int mi = 0; mi < 4; ++mi)
            af[mi] = *(const bf16x8*)(Ab_ + (wr * 64 + mi * 16 + l15) * 64 + cbr);
#pragma unroll
        for (int ni = 0; ni < 4; ++ni)
            bfr[ni] = *(const bf16x8*)(Bb_ + (wc * 64 + ni * 16 + l15) * 64 + cbr);

        if (T + 2 < NT) {
            int nxt = cur + 2;
            if (nxt >= 3) nxt -= 3;
            STAGE(nxt, T + 2);
        }

        LGKMCNT(0);
        __builtin_amdgcn_sched_barrier(0);
        __builtin_amdgcn_s_setprio(1);
#pragma unroll
        for (int mi = 0; mi < 4; ++mi)
#pragma unroll
            for (int ni = 0; ni < 4; ++ni)
                acc[mi][ni] = __builtin_amdgcn_mfma_f32_16x16x32_bf16(
                    af[mi], bfr[ni], acc[mi][ni], 0, 0, 0);
        __builtin_amdgcn_s_setprio(0);

        cur = (cur == 2) ? 0 : cur + 1;
    }

#pragma unroll
    for (int mi = 0; mi < 4; ++mi) {
#pragma unroll
        for (int ni = 0; ni < 4; ++ni) {
            int col = col0 + wc * 64 + ni * 16 + l15;
            float bv = bias ? bias[col] : 0.f;
#pragma unroll
            for (int r = 0; r < 4; ++r) {
                int row = row0 + wr * 64 + mi * 16 + g * 4 + r;
                float v = acc[mi][ni][r] + bv;
                float vp = __shfl_xor(v, 1);
                if (!(l15 & 1)) {
                    unsigned int u = (unsigned int)f2b(v) | ((unsigned int)f2b(vp) << 16);
                    *(unsigned int*)&C16[(long)row * ldc + col] = u;
                }
            }
        }
    }
}

// ---------------------------------------------------------------------------
// 128x64 N-tile variant: same pipeline, gate vmcnt(3), 36KB LDS.
// ---------------------------------------------------------------------------
__global__ __launch_bounds__(256)
void gemm128x64(const unsigned short* __restrict__ A, int lda,
                const unsigned short* __restrict__ B, int ldb,
                const float* __restrict__ bias,
                unsigned short* __restrict__ C16, int ldc,
                int K, int nbx)
{
    __shared__ __align__(16) unsigned short Ab[3][128 * 32];
    __shared__ __align__(16) unsigned short Bb[3][64 * 32];
    int o = blockIdx.x;
    int cpx = gridDim.x >> 3;
    int swz = (o & 7) * cpx + (o >> 3);
    int by = swz / nbx, bx = swz - by * nbx;
    int row0 = by * 128, col0 = bx * 64;

    int t = threadIdx.x;
    int w = t >> 6, l = t & 63, l15 = l & 15, g = l >> 4;
    int wr = w >> 1, wc = w & 1;
    int NT = K >> 5;

    f32x4 acc[4][2];
#pragma unroll
    for (int i = 0; i < 4; ++i)
#pragma unroll
        for (int j = 0; j < 2; ++j) acc[i][j] = (f32x4){0.f, 0.f, 0.f, 0.f};

    auto STAGE = [&](int c, int kt) {
        int k0 = kt * 32;
#pragma unroll
        for (int i = 0; i < 2; ++i) {
            int gi = t + i * 256;
            int row = gi >> 2, cg = gi & 3;
            int cgs = cg ^ ((row >> 1) & 3);
            gload16(&A[(long)(row0 + row) * lda + k0 + cgs * 8], &Ab[c][gi * 8]);
        }
        {
            int gi = t;
            int row = gi >> 2, cg = gi & 3;
            int cgs = cg ^ ((row >> 1) & 3);
            gload16(&B[(long)(col0 + row) * ldb + k0 + cgs * 8], &Bb[c][gi * 8]);
        }
    };

    STAGE(0, 0);
    STAGE(1, 1);

    int cbr = (g ^ ((l15 >> 1) & 3)) * 16;

    int cur = 0;
    for (int T = 0; T < NT; ++T) {
        if (T + 1 < NT) { VMCNT(3); } else { VMCNT(0); }
        __builtin_amdgcn_s_barrier();
        asm volatile("" ::: "memory");

        const char* Ab_ = (const char*)&Ab[cur][0];
        const char* Bb_ = (const char*)&Bb[cur][0];
        bf16x8 af[4], bfr[2];
#pragma unroll
        for (int mi = 0; mi < 4; ++mi)
            af[mi] = *(const bf16x8*)(Ab_ + (wr * 64 + mi * 16 + l15) * 64 + cbr);
#pragma unroll
        for (int ni = 0; ni < 2; ++ni)
            bfr[ni] = *(const bf16x8*)(Bb_ + (wc * 32 + ni * 16 + l15) * 64 + cbr);

        if (T + 2 < NT) {
            int nxt = cur + 2;
            if (nxt >= 3) nxt -= 3;
            STAGE(nxt, T + 2);
        }

        LGKMCNT(0);
        __builtin_amdgcn_sched_barrier(0);
        __builtin_amdgcn_s_setprio(1);
#pragma unroll
        for (int mi = 0; mi < 4; ++mi)
#pragma unroll
            for (int ni = 0; ni < 2; ++ni)
                acc[mi][ni] = __builtin_amdgcn_mfma_f32_16x16x32_bf16(
                    af[mi], bfr[ni], acc[mi][ni], 0, 0, 0);
        __builtin_amdgcn_s_setprio(0);

        cur = (cur == 2) ? 0 : cur + 1;
    }

#pragma unroll
    for (int mi = 0; mi < 4; ++mi) {
#pragma unroll
        for (int ni = 0; ni < 2; ++ni) {
            int col = col0 + wc * 32 + ni * 16 + l15;
            float bv = bias ? bias[col] : 0.f;
#pragma unroll
            for (int r = 0; r < 4; ++r) {
                int row = row0 + wr * 64 + mi * 16 + g * 4 + r;
                float v = acc[mi][ni][r] + bv;
                float vp = __shfl_xor(v, 1);
                if (!(l15 & 1)) {
                    unsigned int u = (unsigned int)f2b(v) | ((unsigned int)f2b(vp) << 16);
                    *(unsigned int*)&C16[(long)row * ldc + col] = u;
                }
            }
        }
    }
}

// ---------------------------------------------------------------------------
// gemm128e: 128x64 triple-buffer pipeline + full epilogue + batch (z).
// act: 0 plain (+resid opt), 1 gelu, 2 split@256.
// ---------------------------------------------------------------------------
__global__ __launch_bounds__(256)
void gemm128e(const unsigned short* __restrict__ A, long sA, int lda,
              const unsigned short* __restrict__ B, long sB, int ldb,
              const float* __restrict__ bias,
              const float* __restrict__ resid, long sR, int ldr,
              float* __restrict__ C32, long sC32, int ldc32,
              unsigned short* __restrict__ C16, long sC16, int ldc16,
              float* __restrict__ C32b, int ldc32b,
              int K, int nbx, int act)
{
    __shared__ __align__(16) unsigned short Ab[3][128 * 32];
    __shared__ __align__(16) unsigned short Bb[3][64 * 32];
    int bz = blockIdx.z;
    const unsigned short* Abase = A + (long)bz * sA;
    const unsigned short* Bbase = B + (long)bz * sB;
    int o = blockIdx.x;
    int cpx = gridDim.x >> 3;
    int swz = (o & 7) * cpx + (o >> 3);
    int by = swz / nbx, bx = swz - by * nbx;
    int row0 = by * 128, col0 = bx * 64;

    int t = threadIdx.x;
    int w = t >> 6, l = t & 63, l15 = l & 15, g = l >> 4;
    int wr = w >> 1, wc = w & 1;
    int NT = K >> 5;

    f32x4 acc[4][2];
#pragma unroll
    for (int i = 0; i < 4; ++i)
#pragma unroll
        for (int j = 0; j < 2; ++j) acc[i][j] = (f32x4){0.f, 0.f, 0.f, 0.f};

    auto STAGE = [&](int c, int kt) {
        int k0 = kt * 32;
#pragma unroll
        for (int i = 0; i < 2; ++i) {
            int gi = t + i * 256;
            int row = gi >> 2, cg = gi & 3;
            int cgs = cg ^ ((row >> 1) & 3);
            gload16(&Abase[(long)(row0 + row) * lda + k0 + cgs * 8], &Ab[c][gi * 8]);
        }
        {
            int gi = t;
            int row = gi >> 2, cg = gi & 3;
            int cgs = cg ^ ((row >> 1) & 3);
            gload16(&Bbase[(long)(col0 + row) * ldb + k0 + cgs * 8], &Bb[c][gi * 8]);
        }
    };

    STAGE(0, 0);
    STAGE(1, 1);

    int cbr = (g ^ ((l15 >> 1) & 3)) * 16;

    int cur = 0;
    for (int T = 0; T < NT; ++T) {
        if (T + 1 < NT) { VMCNT(3); } else { VMCNT(0); }
        __builtin_amdgcn_s_barrier();
        asm volatile("" ::: "memory");

        const char* Ab_ = (const char*)&Ab[cur][0];
        const char* Bb_ = (const char*)&Bb[cur][0];
        bf16x8 af[4], bfr[2];
#pragma unroll
        for (int mi = 0; mi < 4; ++mi)
            af[mi] = *(const bf16x8*)(Ab_ + (wr * 64 + mi * 16 + l15) * 64 + cbr);
#pragma unroll
        for (int ni = 0; ni < 2; ++ni)
            bfr[ni] = *(const bf16x8*)(Bb_ + (wc * 32 + ni * 16 + l15) * 64 + cbr);

        if (T + 2 < NT) {
            int nxt = cur + 2;
            if (nxt >= 3) nxt -= 3;
            STAGE(nxt, T + 2);
        }

        LGKMCNT(0);
        __builtin_amdgcn_sched_barrier(0);
        __builtin_amdgcn_s_setprio(1);
#pragma unroll
        for (int mi = 0; mi < 4; ++mi)
#pragma unroll
            for (int ni = 0; ni < 2; ++ni)
                acc[mi][ni] = __builtin_amdgcn_mfma_f32_16x16x32_bf16(
                    af[mi], bfr[ni], acc[mi][ni], 0, 0, 0);
        __builtin_amdgcn_s_setprio(0);

        cur = (cur == 2) ? 0 : cur + 1;
    }

#pragma unroll
    for (int mi = 0; mi < 4; ++mi) {
#pragma unroll
        for (int ni = 0; ni < 2; ++ni) {
            int col = col0 + wc * 32 + ni * 16 + l15;
            float bv = bias ? bias[col] : 0.f;
#pragma unroll
            for (int r = 0; r < 4; ++r) {
                int row = row0 + wr * 64 + mi * 16 + g * 4 + r;
                float v = acc[mi][ni][r] + bv;
                if (act == 2) {
                    if (col < 256) {
                        C32[(long)row * ldc32 + col] = v;
                    } else {
                        v = gelu_f(v);
                        C32b[(long)row * ldc32b + (col - 256)] = v;
                        C16[(long)row * ldc16 + (col - 256)] = f2b(v);
                    }
                    continue;
                }
                if (act == 1) v = gelu_f(v);
                if (resid) v += resid[(long)bz * sR + (long)row * ldr + col];
                if (C32) C32[(long)bz * sC32 + (long)row * ldc32 + col] = v;
                if (C16) C16[(long)bz * sC16 + (long)row * ldc16 + col] = f2b(v);
            }
        }
    }
}

// ---------------------------------------------------------------------------
// Flash attention v2: 4 waves x 32 q-rows (q-tile 128), kv-tile 64.
// K double-buffered LDS via global_load_lds (counted vmcnt); V reg-staged.
// ---------------------------------------------------------------------------
template <int D>
__global__ __launch_bounds__(256, 2)
void attn_mfma(unsigned short* __restrict__ qkv, int stride, int koff, int voff, float scale)
{
    constexpr int GRL = D / 8;
    constexpr int NITK = (64 * GRL) / 256;
    constexpr int NITV = NITK;
    constexpr int NKS = D / 32;
    constexpr int NF = D / 16;
    constexpr int LV = 72;
    constexpr int LP = 72;
    constexpr int NT = NS / 64;

    __shared__ __align__(16) unsigned short Ks[2][64 * D];
    __shared__ __align__(16) unsigned short Vt[D * LV];
    __shared__ __align__(16) unsigned short Ps[128 * LP];

    int b = blockIdx.z, h = blockIdx.y, qt = blockIdx.x;
    int t = threadIdx.x, w = t >> 6, l = t & 63, l15 = l & 15, g = l >> 4;
    int wq = w * 32;
    long qbase = ((long)b * NS + qt * 128) * stride + h * D;
    long kvbase = (long)b * NS * stride + h * D;

    bf16x8 qreg[2][NKS];
#pragma unroll
    for (int qh = 0; qh < 2; ++qh)
#pragma unroll
        for (int ks = 0; ks < NKS; ++ks)
            qreg[qh][ks] = *(const bf16x8*)&qkv[qbase + (long)(wq + qh * 16 + l15) * stride + g * 8 + ks * 32];

    auto KSTAGE = [&](int c, int kt) {
#pragma unroll
        for (int i = 0; i < NITK; ++i) {
            int gi = t + i * 256;
            int row = gi / GRL, cg = gi % GRL;
            int cgs = cg ^ (row & 7);
            gload16(&qkv[kvbase + (long)(kt * 64 + row) * stride + koff + cgs * 8],
                    &Ks[c][gi * 8]);
        }
    };
    uint4 vp[NITV];
    auto VLOAD = [&](int kt) {
#pragma unroll
        for (int i = 0; i < NITV; ++i) {
            int vgi = t + i * 256;
            int kc = vgi & 63, db = vgi >> 6;
            vp[i] = *(const uint4*)&qkv[kvbase + (long)(kt * 64 + kc) * stride + voff + db * 8];
        }
    };
    auto VWRITE = [&]() {
#pragma unroll
        for (int i = 0; i < NITV; ++i) {
            int vgi = t + i * 256;
            int kc = vgi & 63, db = vgi >> 6;
            uint4 v = vp[i];
            Vt[(db * 8 + 0) * LV + kc] = (unsigned short)(v.x & 0xffff);
            Vt[(db * 8 + 1) * LV + kc] = (unsigned short)(v.x >> 16);
            Vt[(db * 8 + 2) * LV + kc] = (unsigned short)(v.y & 0xffff);
            Vt[(db * 8 + 3) * LV + kc] = (unsigned short)(v.y >> 16);
            Vt[(db * 8 + 4) * LV + kc] = (unsigned short)(v.z & 0xffff);
            Vt[(db * 8 + 5) * LV + kc] = (unsigned short)(v.z >> 16);
            Vt[(db * 8 + 6) * LV + kc] = (unsigned short)(v.w & 0xffff);
            Vt[(db * 8 + 7) * LV + kc] = (unsigned short)(v.w >> 16);
        }
    };

    KSTAGE(0, 0);
    VLOAD(0);
    KSTAGE(1, 1);
    if constexpr (NITK == 4) { VMCNT(4); } else { VMCNT(2); }
    VWRITE();
    LGKMCNT(0);
    __builtin_amdgcn_sched_barrier(0);
    __builtin_amdgcn_s_barrier();

    float m_run[2] = {-INFINITY, -INFINITY};
    float l_run[2] = {0.f, 0.f};
    f32x4 zero4 = {0.f, 0.f, 0.f, 0.f};
    f32x4 oacc[2][NF];
#pragma unroll
    for (int qh = 0; qh < 2; ++qh)
#pragma unroll
        for (int nf = 0; nf < NF; ++nf) oacc[qh][nf] = zero4;

    int xr = (l15 & 7) << 4;
    for (int kt = 0; kt < NT; ++kt) {
        if (kt + 1 < NT) VLOAD(kt + 1);

        const char* ksb = (const char*)&Ks[kt & 1][0];
        f32x4 st[4][2];
#pragma unroll
        for (int f = 0; f < 4; ++f)
#pragma unroll
            for (int qh = 0; qh < 2; ++qh) st[f][qh] = zero4;
#pragma unroll
        for (int ks = 0; ks < NKS; ++ks) {
#pragma unroll
            for (int f = 0; f < 4; ++f) {
                int cb = (g * 16 + ks * 64) ^ xr;
                bf16x8 a = *(const bf16x8*)(ksb + (f * 16 + l15) * (D * 2) + cb);
#pragma unroll
                for (int qh = 0; qh < 2; ++qh)
                    st[f][qh] = __builtin_amdgcn_mfma_f32_16x16x32_bf16(a, qreg[qh][ks], st[f][qh], 0, 0, 0);
            }
        }
#pragma unroll
        for (int qh = 0; qh < 2; ++qh) {
            float pm = -INFINITY;
#pragma unroll
            for (int f = 0; f < 4; ++f) {
                st[f][qh] *= scale;
#pragma unroll
                for (int r = 0; r < 4; ++r) pm = fmaxf(pm, st[f][qh][r]);
            }
            pm = fmaxf(pm, __shfl_xor(pm, 16));
            pm = fmaxf(pm, __shfl_xor(pm, 32));
            float mn = fmaxf(m_run[qh], pm);
            float corr = __expf(m_run[qh] - mn);
            float rs = 0.f;
#pragma unroll
            for (int f = 0; f < 4; ++f) {
                float p0 = __expf(st[f][qh][0] - mn);
                float p1 = __expf(st[f][qh][1] - mn);
                float p2 = __expf(st[f][qh][2] - mn);
                float p3 = __expf(st[f][qh][3] - mn);
                rs += (p0 + p1) + (p2 + p3);
                ushort4 pw;
                pw.x = f2b(p0); pw.y = f2b(p1); pw.z = f2b(p2); pw.w = f2b(p3);
                *(ushort4*)&Ps[(wq + qh * 16 + l15) * LP + f * 16 + g * 4] = pw;
            }
            rs += __shfl_xor(rs, 16);
            rs += __shfl_xor(rs, 32);
            l_run[qh] = l_run[qh] * corr + rs;
            m_run[qh] = mn;
            float corrO[4];
#pragma unroll
            for (int r = 0; r < 4; ++r) corrO[r] = __shfl(corr, g * 4 + r);
#pragma unroll
            for (int nf = 0; nf < NF; ++nf)
#pragma unroll
                for (int r = 0; r < 4; ++r) oacc[qh][nf][r] *= corrO[r];
        }
#pragma unroll
        for (int ks2 = 0; ks2 < 2; ++ks2) {
            bf16x8 vb[NF];
#pragma unroll
            for (int nf = 0; nf < NF; ++nf)
                vb[nf] = *(const bf16x8*)&Vt[(nf * 16 + l15) * LV + ks2 * 32 + g * 8];
#pragma unroll
            for (int qh = 0; qh < 2; ++qh) {
                bf16x8 pa = *(const bf16x8*)&Ps[(wq + qh * 16 + l15) * LP + ks2 * 32 + g * 8];
#pragma unroll
                for (int nf = 0; nf < NF; ++nf)
                    oacc[qh][nf] = __builtin_amdgcn_mfma_f32_16x16x32_bf16(pa, vb[nf], oacc[qh][nf], 0, 0, 0);
            }
        }

        if (kt + 1 < NT) {
            LGKMCNT(0);
            __builtin_amdgcn_sched_barrier(0);
            __builtin_amdgcn_s_barrier();
            if (kt + 2 < NT) {
                KSTAGE(kt & 1, kt + 2);
                if constexpr (NITK == 4) { VMCNT(4); } else { VMCNT(2); }
            } else {
                VMCNT(0);
            }
            VWRITE();
            LGKMCNT(0);
            __builtin_amdgcn_sched_barrier(0);
            __builtin_amdgcn_s_barrier();
        }
    }

#pragma unroll
    for (int qh = 0; qh < 2; ++qh) {
        float lo[4];
#pragma unroll
        for (int r = 0; r < 4; ++r) lo[r] = __shfl(l_run[qh], g * 4 + r);
#pragma unroll
        for (int nf = 0; nf < NF; ++nf)
#pragma unroll
            for (int r = 0; r < 4; ++r) {
                float o = oacc[qh][nf][r] / lo[r];
                qkv[qbase + (long)(wq + qh * 16 + g * 4 + r) * stride + nf * 16 + l15] = f2b(o);
            }
    }
}

// ---------------------------------------------------------------------------
__global__ __launch_bounds__(256)
void maxpart_aff_kernel(const float* __restrict__ aff, float* __restrict__ part)
{
    int sc = blockIdx.x, b = blockIdx.y, t = threadIdx.x;
    float m = -INFINITY;
    for (int s = sc * 32; s < (sc + 1) * 32; ++s)
        m = fmaxf(m, aff[((long)b * NS + s) * NIN + t]);
    part[(b * 32 + sc) * NIN + t] = m;
}

__global__ __launch_bounds__(256)
void rank_input_kernel(const float* __restrict__ part, int* __restrict__ idx_out,
                       float* __restrict__ w_out)
{
    int b = blockIdx.x, t = threadIdx.x;
    __shared__ float lg[256], rv[256];
    float m = part[(b * 32) * NIN + t];
#pragma unroll
    for (int sc = 1; sc < 32; ++sc) m = fmaxf(m, part[(b * 32 + sc) * NIN + t]);
    float l = m * 0.5f;
    lg[t] = l;
    rv[t] = l;
    __syncthreads();
    for (int off = 128; off; off >>= 1) {
        if (t < off) rv[t] = fmaxf(rv[t], rv[t + off]);
        __syncthreads();
    }
    float mx = rv[0];
    __syncthreads();
    float e = expf(l - mx);
    rv[t] = e;
    __syncthreads();
    for (int off = 128; off; off >>= 1) {
        if (t < off) rv[t] += rv[t + off];
        __syncthreads();
    }
    float Zs = rv[0];
    float soft = e / Zs;
    __syncthreads();
    int rank = 0;
    for (int j = 0; j < 256; ++j) {
        float vj = lg[j];
        rank += (vj > l) || (vj == l && j < t);
    }
    rv[t] = (rank < KIN) ? soft : 0.f;
    __syncthreads();
    for (int off = 128; off; off >>= 1) {
        if (t < off) rv[t] += rv[t + off];
        __syncthreads();
    }
    float msum = rv[0];
    if (rank < KIN) {
        idx_out[b * KIN + rank] = t;
        w_out[b * KIN + rank] = soft / (msum + 1e-8f);
    }
}

__global__ __launch_bounds__(512)
void rank_proc_kernel(const float* __restrict__ finals, int* __restrict__ pidx)
{
    int b = blockIdx.x, t = threadIdx.x;
    __shared__ float v[512];
    float xv = finals[b * NPROC + t];
    v[t] = xv;
    __syncthreads();
    int rank = 0;
    for (int j = 0; j < 512; ++j) {
        float vj = v[j];
        rank += (vj > xv) || (vj == xv && j < t);
    }
    if (rank < KPROC) pidx[b * KPROC + rank] = t;
}

// ---------------------------------------------------------------------------
// LN + routed gather, wave-per-row. Block = 4 waves = 4 rows; grid = 2048.
// ---------------------------------------------------------------------------
__global__ __launch_bounds__(256)
void ln_gather_kernel(const float* __restrict__ a, const unsigned short* __restrict__ bsrc,
                      const float* __restrict__ gg, const float* __restrict__ be,
                      const int* __restrict__ idx_in, const float* __restrict__ w_sel,
                      unsigned short* __restrict__ sel_acts)
{
    int w = threadIdx.x >> 6, l = threadIdx.x & 63;
    long row = (long)blockIdx.x * 4 + w;
    int b = (int)(row >> 10);
    __shared__ float lnv[4][256];

    float4 av = *(const float4*)&a[row * 256 + l * 4];
    ushort4 bu = *(const ushort4*)&bsrc[row * 256 + l * 4];
    float v0 = av.x + b2f(bu.x);
    float v1 = av.y + b2f(bu.y);
    float v2 = av.z + b2f(bu.z);
    float v3 = av.w + b2f(bu.w);
    float s = (v0 + v1) + (v2 + v3);
#pragma unroll
    for (int off = 1; off < 64; off <<= 1) s += __shfl_xor(s, off);
    float mean = s * (1.f / 256.f);
    float d0 = v0 - mean, d1 = v1 - mean, d2 = v2 - mean, d3 = v3 - mean;
    float ss = (d0 * d0 + d1 * d1) + (d2 * d2 + d3 * d3);
#pragma unroll
    for (int off = 1; off < 64; off <<= 1) ss += __shfl_xor(ss, off);
    float rstd = rsqrtf(ss * (1.f / 256.f) + 1e-5f);
    float4 gv = *(const float4*)&gg[l * 4];
    float4 bev = *(const float4*)&be[l * 4];
    lnv[w][l * 4 + 0] = d0 * rstd * gv.x + bev.x;
    lnv[w][l * 4 + 1] = d1 * rstd * gv.y + bev.y;
    lnv[w][l * 4 + 2] = d2 * rstd * gv.z + bev.z;
    lnv[w][l * 4 + 3] = d3 * rstd * gv.w + bev.w;
    int id0 = idx_in[b * KIN + l];
    int id1 = idx_in[b * KIN + l + 64];
    sel_acts[row * KIN + l] = f2b(lnv[w][id0] * w_sel[b * KIN + l]);
    sel_acts[row * KIN + l + 64] = f2b(lnv[w][id1] * w_sel[b * KIN + l + 64]);
}

__global__ void gather_sel_cw_b(const float* __restrict__ comb_w, const int* __restrict__ idx_in,
                                unsigned short* __restrict__ sel_cw)
{
    int gidx = blockIdx.x * 256 + threadIdx.x;
    int b = gidx >> 16;
    int rem = gidx & 65535;
    int pb = rem >> 7, j = rem & 127;
    sel_cw[gidx] = f2b(comb_w[pb * NIN + idx_in[b * KIN + j]]);
}

__global__ void gather_sel_proc_b(const unsigned short* __restrict__ proc_acts,
                                  const int* __restrict__ pidx,
                                  unsigned short* __restrict__ sel_proc)
{
    int s = blockIdx.x, b = blockIdx.y, j = threadIdx.x;
    long row = (long)b * NS + s;
    sel_proc[row * KPROC + j] = proc_acts[row * NPROC + pidx[b * KPROC + j]];
}

__global__ void gather_sel_projT(const float* __restrict__ out_proj_w, const int* __restrict__ pidx,
                                 unsigned short* __restrict__ selT)
{
    int gidx = blockIdx.x * 256 + threadIdx.x;
    int b = gidx >> 15;
    int rem = gidx & 32767;
    int d = rem >> 5;
    int kp0 = (rem & 31) * 8;
    unsigned int u[4];
#pragma unroll
    for (int i = 0; i < 4; ++i) {
        unsigned short e0 = f2b(out_proj_w[(long)pidx[b * KPROC + kp0 + 2 * i] * ND + d]);
        unsigned short e1 = f2b(out_proj_w[(long)pidx[b * KPROC + kp0 + 2 * i + 1] * ND + d]);
        u[i] = (unsigned int)e0 | ((unsigned int)e1 << 16);
    }
    uint4 o; o.x = u[0]; o.y = u[1]; o.z = u[2]; o.w = u[3];
    *(uint4*)&selT[((long)b * ND + d) * KPROC + kp0] = o;
}

__global__ __launch_bounds__(512)
void maxpart_kernel(const unsigned short* __restrict__ proc, float* __restrict__ part)
{
    int sc = blockIdx.x, b = blockIdx.y, t = threadIdx.x;
    float m = -INFINITY;
    for (int s = sc * 32; s < (sc + 1) * 32; ++s)
        m = fmaxf(m, b2f(proc[((long)b * NS + s) * NPROC + t]));
    part[(b * 32 + sc) * NPROC + t] = m;
}

// ---------------------------------------------------------------------------
// relevance split: rel1 then finals (wave-per-p, coalesced a2)
// ---------------------------------------------------------------------------
__global__ __launch_bounds__(512)
void rel1_kernel(const int* __restrict__ idx_in, const float* __restrict__ a1w,
                 const float* __restrict__ a1b, float* __restrict__ rel1g)
{
    int b = blockIdx.x, t = threadIdx.x;
    __shared__ int sidx[KIN];
    if (t < KIN) sidx[t] = idx_in[b * KIN + t];
    __syncthreads();
    float r1 = a1b[t];
    const float* a1row = a1w + (long)t * NIN;
    for (int j = 0; j < KIN; ++j) r1 += a1row[sidx[j]];
    rel1g[b * 512 + t] = gelu_f(r1);
}

__global__ __launch_bounds__(256)
void finals_kernel(const float* __restrict__ maxpart, const float* __restrict__ rel1g,
                   const float* __restrict__ a2w, const float* __restrict__ a2b,
                   float* __restrict__ finals)
{
    int b = blockIdx.y;
    int w = threadIdx.x >> 6, l = threadIdx.x & 63;
    __shared__ float r1[512];
    for (int i = threadIdx.x; i < 512; i += 256) r1[i] = rel1g[b * 512 + i];
    __syncthreads();
#pragma unroll 1
    for (int pi = 0; pi < 16; ++pi) {
        int p = blockIdx.x * 64 + w * 16 + pi;
        const float* a2row = a2w + (long)p * 512;
        float acc = 0.f;
#pragma unroll
        for (int i = 0; i < 8; ++i)
            acc += a2row[l + i * 64] * r1[l + i * 64];
#pragma unroll
        for (int off = 1; off < 64; off <<= 1) acc += __shfl_xor(acc, off);
        float m = (l < 32) ? maxpart[((long)b * 32 + l) * NPROC + p] : -INFINITY;
#pragma unroll
        for (int off = 1; off < 32; off <<= 1) m = fmaxf(m, __shfl_xor(m, off));
        if (l == 0) {
            float r = acc + a2b[p];
            float sig = 1.f / (1.f + expf(-r));
            finals[b * NPROC + p] = m * sig;
        }
    }
}

// ---------------------------------------------------------------------------
extern "C" void kernel_launch(void* const* d_in, const int* in_sizes, int n_in,
                              void* d_out, int out_size, void* d_ws, size_t ws_size,
                              hipStream_t stream)
{
    const float* x       = (const float*)d_in[0];
    const float* r_in_w  = (const float*)d_in[1];
    const float* r_in_b  = (const float*)d_in[2];
    const float* r_out_w = (const float*)d_in[3];
    const float* r_out_b = (const float*)d_in[4];
    const float* aff_w   = (const float*)d_in[5];
    const float* aff_b   = (const float*)d_in[6];
    const float* patterns= (const float*)d_in[7];
    const float* i_in_w  = (const float*)d_in[8];
    const float* i_in_b  = (const float*)d_in[9];
    const float* i_out_w = (const float*)d_in[10];
    const float* i_out_b = (const float*)d_in[11];
    const float* ln_g    = (const float*)d_in[12];
    const float* ln_b    = (const float*)d_in[13];
    const float* comb_w  = (const float*)d_in[14];
    const float* out_proj_w = (const float*)d_in[15];
    const float* a1w     = (const float*)d_in[16];
    const float* a1b     = (const float*)d_in[17];
    const float* a2w     = (const float*)d_in[18];
    const float* a2b     = (const float*)d_in[19];
    float* out = (float*)d_out;

    char* ws = (char*)d_ws;
    unsigned short* qkv1b    = (unsigned short*)(ws + 0);
    unsigned short* contextb = (unsigned short*)(ws + 50331648);
    unsigned short* xb       = (unsigned short*)(ws + 67108864);
    unsigned short* w_rin_b  = (unsigned short*)(ws + 83886080);
    unsigned short* w_rout_b = (unsigned short*)(ws + 90177536);
    unsigned short* w_aff_b  = (unsigned short*)(ws + 92274688);
    unsigned short* patt_b   = (unsigned short*)(ws + 92798976);
    unsigned short* w_iin_b  = (unsigned short*)(ws + 93323264);
    unsigned short* w_iout_b = (unsigned short*)(ws + 93716480);
    float* w_sel   = (float*)(ws + 93855744);
    int*   idx_in  = (int*)(ws + 93859840);
    float* finals  = (float*)(ws + 93863936);
    int*   pidx    = (int*)(ws + 93880320);
    float* affin   = (float*)(ws + 94019584);
    float* acts0   = (float*)(ws + 102408192);
    unsigned short* acts0b = (unsigned short*)(ws + 110796800);
    unsigned short* qkv2b  = (unsigned short*)(ws + 114991104);
    unsigned short* attn2projb = (unsigned short*)(ws + 0);
    unsigned short* proc_actsb = (unsigned short*)(ws + 16777216);
    unsigned short* sel_actsb = (unsigned short*)(ws + 33554432);
    unsigned short* sel_cwb   = (unsigned short*)(ws + 35651584);
    unsigned short* sel_procb = (unsigned short*)(ws + 36700160);
    unsigned short* sel_projT = (unsigned short*)(ws + 40894464);
    float* biascat  = (float*)(ws + 45088768);
    float* part_aff = (float*)(ws + 45091840);
    float* maxpart  = (float*)(ws + 45353984);
    float* rel1g    = (float*)(ws + 45878272);

    // 0. all conversions + biascat init in one launch
    cvt_all_kernel<<<2048, 256, 0, stream>>>(
        x, r_in_w, r_out_w, aff_w, patterns, i_in_w, i_out_w, aff_b,
        xb, w_rin_b, w_rout_b, w_aff_b, patt_b, w_iin_b, w_iout_b, biascat);

    // 1. qkv1 = x @ r_in_w^T + b (1536 blocks)
    gemm128s<<<1536, 256, 0, stream>>>(xb, ND, w_rin_b, ND, r_in_b, qkv1b, 3 * ND, ND, 24);
    // 2. MHA-1
    attn_mfma<128><<<dim3(8, 8, 8), 256, 0, stream>>>(qkv1b, 3 * ND, ND, 2 * ND, 0.088388347648318447f);
    // 3. context (128x64 tile, 1024 blocks)
    gemm128x64<<<1024, 256, 0, stream>>>(qkv1b, 3 * ND, w_rout_b, ND, r_out_b, contextb, ND, ND, 16);
    // 4. fused affinity+patterns (split epilogue, 512 blocks)
    gemm128e<<<dim3(512, 1, 1), 256, 0, stream>>>(
        contextb, 0, ND, w_aff_b, 0, ND, biascat, nullptr, 0, 0,
        affin, 0, NIN, acts0b, 0, NIN, acts0, NIN, ND, 8, 2);
    // 5. routing
    maxpart_aff_kernel<<<dim3(32, NB), 256, 0, stream>>>(affin, part_aff);
    rank_input_kernel<<<NB, 256, 0, stream>>>(part_aff, idx_in, w_sel);
    // 6. qkv2 (768 blocks)
    gemm128x64<<<768, 256, 0, stream>>>(acts0b, NIN, w_iin_b, NIN, i_in_b, qkv2b, 3 * NIN, NIN, 12);
    // 7. MHA-2
    attn_mfma<64><<<dim3(8, 4, 8), 256, 0, stream>>>(qkv2b, 3 * NIN, NIN, 2 * NIN, 0.125f);
    // 8. attn2 out-proj -> bf16 (256 blocks)
    gemm128e<<<dim3(256, 1, 1), 256, 0, stream>>>(
        qkv2b, 0, 3 * NIN, w_iout_b, 0, NIN, i_out_b, nullptr, 0, 0,
        nullptr, 0, 0, attn2projb, 0, NIN, nullptr, 0, NIN, 4, 0);
    // 9. LN + routed gather (wave-per-row, 2048 blocks)
    ln_gather_kernel<<<2048, 256, 0, stream>>>(acts0, attn2projb, ln_g, ln_b,
                                               idx_in, w_sel, sel_actsb);
    gather_sel_cw_b<<<2048, 256, 0, stream>>>(comb_w, idx_in, sel_cwb);
    // 10. proc_acts -> bf16 (batched, 64 x 8)
    gemm128e<<<dim3(64, 1, NB), 256, 0, stream>>>(
        sel_actsb, (long)NS * KIN, KIN, sel_cwb, (long)NPROC * KIN, KIN,
        nullptr, nullptr, 0, 0,
        nullptr, 0, 0, proc_actsb, (long)NS * NPROC, NPROC, nullptr, 0, KIN, 8, 1);
    // 11. final scores + top-256
    maxpart_kernel<<<dim3(32, NB), 512, 0, stream>>>(proc_actsb, maxpart);
    rel1_kernel<<<NB, 512, 0, stream>>>(idx_in, a1w, a1b, rel1g);
    finals_kernel<<<dim3(8, NB), 256, 0, stream>>>(maxpart, rel1g, a2w, a2b, finals);
    rank_proc_kernel<<<NB, 512, 0, stream>>>(finals, pidx);
    // 12. output gathers + GEMM + residual (batched, 128 x 8)
    gather_sel_proc_b<<<dim3(NS, NB), KPROC, 0, stream>>>(proc_actsb, pidx, sel_procb);
    gather_sel_projT<<<1024, 256, 0, stream>>>(out_proj_w, pidx, sel_projT);
    gemm128e<<<dim3(128, 1, NB), 256, 0, stream>>>(
        sel_procb, (long)NS * KPROC, KPROC, sel_projT, (long)ND * KPROC, KPROC,
        nullptr, x, (long)NS * ND, ND,
        out, (long)NS * ND, ND, nullptr, 0, 0, nullptr, 0, KPROC, 16, 0);
    (void)in_sizes; (void)n_in; (void)out_size; (void)ws_size;
}

// Round 25
// 399.162 us; speedup vs baseline: 1.1189x; 1.0168x over previous
//
#include <hip/hip_runtime.h>
#include <hip/hip_bf16.h>
#include <math.h>

constexpr int NB = 8, NS = 1024, ND = 1024, NIN = 256, NPROC = 512, KIN = 128, KPROC = 256;

typedef __attribute__((ext_vector_type(8))) short bf16x8;
typedef __attribute__((ext_vector_type(4))) float f32x4;

#define VMCNT(n) asm volatile("s_waitcnt vmcnt(" #n ")" ::: "memory")
#define LGKMCNT(n) asm volatile("s_waitcnt lgkmcnt(" #n ")" ::: "memory")

__device__ inline float gelu_f(float x) {
    return 0.5f * x * (1.0f + erff(x * 0.7071067811865476f));
}
__device__ inline unsigned short f2b(float f) {
    __hip_bfloat16 h = __float2bfloat16(f);
    return *reinterpret_cast<unsigned short*>(&h);
}
__device__ inline float b2f(unsigned short u) {
    unsigned int v = (unsigned int)u << 16;
    return __uint_as_float(v);
}
__device__ inline void gload16(const void* g, void* l) {
    __builtin_amdgcn_global_load_lds(
        (const __attribute__((address_space(1))) void*)g,
        (__attribute__((address_space(3))) void*)l, 16, 0, 0);
}

// ---------------------------------------------------------------------------
// Fused f32->bf16 conversions + biascat init.
// ---------------------------------------------------------------------------
__global__ __launch_bounds__(256)
void cvt_all_kernel(const float* __restrict__ x, const float* __restrict__ rin,
                    const float* __restrict__ rout, const float* __restrict__ affw,
                    const float* __restrict__ patt, const float* __restrict__ iin,
                    const float* __restrict__ iout, const float* __restrict__ aff_b,
                    unsigned short* __restrict__ xb, unsigned short* __restrict__ rinb,
                    unsigned short* __restrict__ routb, unsigned short* __restrict__ affbw,
                    unsigned short* __restrict__ pattb, unsigned short* __restrict__ iinb,
                    unsigned short* __restrict__ ioutb, float* __restrict__ biascat)
{
    if (blockIdx.x == 0) {
        int t = threadIdx.x;
        biascat[t] = aff_b[t];
        biascat[256 + t] = 0.f;
    }
    long gi = (long)blockIdx.x * 256 + threadIdx.x;
    long stride = (long)gridDim.x * 256;
    for (; gi < 3342336; gi += stride) {
        const float4* s; ushort4* d; long off;
        if (gi < 2097152)      { s = (const float4*)x;    d = (ushort4*)xb;    off = gi; }
        else if (gi < 2883584) { s = (const float4*)rin;  d = (ushort4*)rinb;  off = gi - 2097152; }
        else if (gi < 3145728) { s = (const float4*)rout; d = (ushort4*)routb; off = gi - 2883584; }
        else if (gi < 3211264) { s = (const float4*)affw; d = (ushort4*)affbw; off = gi - 3145728; }
        else if (gi < 3276800) { s = (const float4*)patt; d = (ushort4*)pattb; off = gi - 3211264; }
        else if (gi < 3325952) { s = (const float4*)iin;  d = (ushort4*)iinb;  off = gi - 3276800; }
        else                   { s = (const float4*)iout; d = (ushort4*)ioutb; off = gi - 3325952; }
        float4 v = s[off];
        ushort4 o;
        o.x = f2b(v.x); o.y = f2b(v.y); o.z = f2b(v.z); o.w = f2b(v.w);
        d[off] = o;
    }
}

// ---------------------------------------------------------------------------
// 128x128 bf16 MFMA GEMM, BK=32 triple-buffer, one barrier/tile, 4 waves,
// counted vmcnt + 2-bit XOR swizzle + XCD grid swizzle. 48KB LDS.
// ---------------------------------------------------------------------------
__global__ __launch_bounds__(256)
void gemm128s(const unsigned short* __restrict__ A, int lda,
              const unsigned short* __restrict__ B, int ldb,
              const float* __restrict__ bias,
              unsigned short* __restrict__ C16, int ldc,
              int K, int nbx)
{
    __shared__ __align__(16) unsigned short Ab[3][128 * 32];
    __shared__ __align__(16) unsigned short Bb[3][128 * 32];
    int o = blockIdx.x;
    int cpx = gridDim.x >> 3;
    int swz = (o & 7) * cpx + (o >> 3);
    int by = swz / nbx, bx = swz - by * nbx;
    int row0 = by * 128, col0 = bx * 128;

    int t = threadIdx.x;
    int w = t >> 6, l = t & 63, l15 = l & 15, g = l >> 4;
    int wr = w >> 1, wc = w & 1;
    int NT = K >> 5;

    f32x4 acc[4][4];
#pragma unroll
    for (int i = 0; i < 4; ++i)
#pragma unroll
        for (int j = 0; j < 4; ++j) acc[i][j] = (f32x4){0.f, 0.f, 0.f, 0.f};

    auto STAGE = [&](int c, int kt) {
        int k0 = kt * 32;
#pragma unroll
        for (int i = 0; i < 2; ++i) {
            int gi = t + i * 256;
            int row = gi >> 2, cg = gi & 3;
            int cgs = cg ^ ((row >> 1) & 3);
            gload16(&A[(long)(row0 + row) * lda + k0 + cgs * 8], &Ab[c][gi * 8]);
        }
#pragma unroll
        for (int i = 0; i < 2; ++i) {
            int gi = t + i * 256;
            int row = gi >> 2, cg = gi & 3;
            int cgs = cg ^ ((row >> 1) & 3);
            gload16(&B[(long)(col0 + row) * ldb + k0 + cgs * 8], &Bb[c][gi * 8]);
        }
    };

    STAGE(0, 0);
    STAGE(1, 1);

    int cbr = (g ^ ((l15 >> 1) & 3)) * 16;

    int cur = 0;
    for (int T = 0; T < NT; ++T) {
        if (T + 1 < NT) { VMCNT(4); } else { VMCNT(0); }
        __builtin_amdgcn_s_barrier();
        asm volatile("" ::: "memory");

        const char* Ab_ = (const char*)&Ab[cur][0];
        const char* Bb_ = (const char*)&Bb[cur][0];
        bf16x8 af[4], bfr[4];
#pragma unroll
        for (int mi = 0; mi < 4; ++mi)
            af[mi] = *(const bf16x8*)(Ab_ + (wr * 64 + mi * 16 + l15) * 64 + cbr);
#pragma unroll
        for (int ni = 0; ni < 4; ++ni)
            bfr[ni] = *(const bf16x8*)(Bb_ + (wc * 64 + ni * 16 + l15) * 64 + cbr);

        if (T + 2 < NT) {
            int nxt = cur + 2;
            if (nxt >= 3) nxt -= 3;
            STAGE(nxt, T + 2);
        }

        LGKMCNT(0);
        __builtin_amdgcn_sched_barrier(0);
        __builtin_amdgcn_s_setprio(1);
#pragma unroll
        for (int mi = 0; mi < 4; ++mi)
#pragma unroll
            for (int ni = 0; ni < 4; ++ni)
                acc[mi][ni] = __builtin_amdgcn_mfma_f32_16x16x32_bf16(
                    af[mi], bfr[ni], acc[mi][ni], 0, 0, 0);
        __builtin_amdgcn_s_setprio(0);

        cur = (cur == 2) ? 0 : cur + 1;
    }

#pragma unroll
    for (int mi = 0; mi < 4; ++mi) {
#pragma unroll
        for (int ni = 0; ni < 4; ++ni) {
            int col = col0 + wc * 64 + ni * 16 + l15;
            float bv = bias ? bias[col] : 0.f;
#pragma unroll
            for (int r = 0; r < 4; ++r) {
                int row = row0 + wr * 64 + mi * 16 + g * 4 + r;
                float v = acc[mi][ni][r] + bv;
                float vp = __shfl_xor(v, 1);
                if (!(l15 & 1)) {
                    unsigned int u = (unsigned int)f2b(v) | ((unsigned int)f2b(vp) << 16);
                    *(unsigned int*)&C16[(long)row * ldc + col] = u;
                }
            }
        }
    }
}

// ---------------------------------------------------------------------------
// 128x64 N-tile variant: same pipeline, gate vmcnt(3), 36KB LDS.
// ---------------------------------------------------------------------------
__global__ __launch_bounds__(256)
void gemm128x64(const unsigned short* __restrict__ A, int lda,
                const unsigned short* __restrict__ B, int ldb,
                const float* __restrict__ bias,
                unsigned short* __restrict__ C16, int ldc,
                int K, int nbx)
{
    __shared__ __align__(16) unsigned short Ab[3][128 * 32];
    __shared__ __align__(16) unsigned short Bb[3][64 * 32];
    int o = blockIdx.x;
    int cpx = gridDim.x >> 3;
    int swz = (o & 7) * cpx + (o >> 3);
    int by = swz / nbx, bx = swz - by * nbx;
    int row0 = by * 128, col0 = bx * 64;

    int t = threadIdx.x;
    int w = t >> 6, l = t & 63, l15 = l & 15, g = l >> 4;
    int wr = w >> 1, wc = w & 1;
    int NT = K >> 5;

    f32x4 acc[4][2];
#pragma unroll
    for (int i = 0; i < 4; ++i)
#pragma unroll
        for (int j = 0; j < 2; ++j) acc[i][j] = (f32x4){0.f, 0.f, 0.f, 0.f};

    auto STAGE = [&](int c, int kt) {
        int k0 = kt * 32;
#pragma unroll
        for (int i = 0; i < 2; ++i) {
            int gi = t + i * 256;
            int row = gi >> 2, cg = gi & 3;
            int cgs = cg ^ ((row >> 1) & 3);
            gload16(&A[(long)(row0 + row) * lda + k0 + cgs * 8], &Ab[c][gi * 8]);
        }
        {
            int gi = t;
            int row = gi >> 2, cg = gi & 3;
            int cgs = cg ^ ((row >> 1) & 3);
            gload16(&B[(long)(col0 + row) * ldb + k0 + cgs * 8], &Bb[c][gi * 8]);
        }
    };

    STAGE(0, 0);
    STAGE(1, 1);

    int cbr = (g ^ ((l15 >> 1) & 3)) * 16;

    int cur = 0;
    for (int T = 0; T < NT; ++T) {
        if (T + 1 < NT) { VMCNT(3); } else { VMCNT(0); }
        __builtin_amdgcn_s_barrier();
        asm volatile("" ::: "memory");

        const char* Ab_ = (const char*)&Ab[cur][0];
        const char* Bb_ = (const char*)&Bb[cur][0];
        bf16x8 af[4], bfr[2];
#pragma unroll
        for (int mi = 0; mi < 4; ++mi)
            af[mi] = *(const bf16x8*)(Ab_ + (wr * 64 + mi * 16 + l15) * 64 + cbr);
#pragma unroll
        for (int ni = 0; ni < 2; ++ni)
            bfr[ni] = *(const bf16x8*)(Bb_ + (wc * 32 + ni * 16 + l15) * 64 + cbr);

        if (T + 2 < NT) {
            int nxt = cur + 2;
            if (nxt >= 3) nxt -= 3;
            STAGE(nxt, T + 2);
        }

        LGKMCNT(0);
        __builtin_amdgcn_sched_barrier(0);
        __builtin_amdgcn_s_setprio(1);
#pragma unroll
        for (int mi = 0; mi < 4; ++mi)
#pragma unroll
            for (int ni = 0; ni < 2; ++ni)
                acc[mi][ni] = __builtin_amdgcn_mfma_f32_16x16x32_bf16(
                    af[mi], bfr[ni], acc[mi][ni], 0, 0, 0);
        __builtin_amdgcn_s_setprio(0);

        cur = (cur == 2) ? 0 : cur + 1;
    }

#pragma unroll
    for (int mi = 0; mi < 4; ++mi) {
#pragma unroll
        for (int ni = 0; ni < 2; ++ni) {
            int col = col0 + wc * 32 + ni * 16 + l15;
            float bv = bias ? bias[col] : 0.f;
#pragma unroll
            for (int r = 0; r < 4; ++r) {
                int row = row0 + wr * 64 + mi * 16 + g * 4 + r;
                float v = acc[mi][ni][r] + bv;
                float vp = __shfl_xor(v, 1);
                if (!(l15 & 1)) {
                    unsigned int u = (unsigned int)f2b(v) | ((unsigned int)f2b(vp) << 16);
                    *(unsigned int*)&C16[(long)row * ldc + col] = u;
                }
            }
        }
    }
}

// ---------------------------------------------------------------------------
// gemm128e: 128x64 triple-buffer pipeline + full epilogue + batch (z).
// act: 0 plain (+resid opt), 1 gelu, 2 split@256.
// ---------------------------------------------------------------------------
__global__ __launch_bounds__(256)
void gemm128e(const unsigned short* __restrict__ A, long sA, int lda,
              const unsigned short* __restrict__ B, long sB, int ldb,
              const float* __restrict__ bias,
              const float* __restrict__ resid, long sR, int ldr,
              float* __restrict__ C32, long sC32, int ldc32,
              unsigned short* __restrict__ C16, long sC16, int ldc16,
              float* __restrict__ C32b, int ldc32b,
              int K, int nbx, int act)
{
    __shared__ __align__(16) unsigned short Ab[3][128 * 32];
    __shared__ __align__(16) unsigned short Bb[3][64 * 32];
    int bz = blockIdx.z;
    const unsigned short* Abase = A + (long)bz * sA;
    const unsigned short* Bbase = B + (long)bz * sB;
    int o = blockIdx.x;
    int cpx = gridDim.x >> 3;
    int swz = (o & 7) * cpx + (o >> 3);
    int by = swz / nbx, bx = swz - by * nbx;
    int row0 = by * 128, col0 = bx * 64;

    int t = threadIdx.x;
    int w = t >> 6, l = t & 63, l15 = l & 15, g = l >> 4;
    int wr = w >> 1, wc = w & 1;
    int NT = K >> 5;

    f32x4 acc[4][2];
#pragma unroll
    for (int i = 0; i < 4; ++i)
#pragma unroll
        for (int j = 0; j < 2; ++j) acc[i][j] = (f32x4){0.f, 0.f, 0.f, 0.f};

    auto STAGE = [&](int c, int kt) {
        int k0 = kt * 32;
#pragma unroll
        for (int i = 0; i < 2; ++i) {
            int gi = t + i * 256;
            int row = gi >> 2, cg = gi & 3;
            int cgs = cg ^ ((row >> 1) & 3);
            gload16(&Abase[(long)(row0 + row) * lda + k0 + cgs * 8], &Ab[c][gi * 8]);
        }
        {
            int gi = t;
            int row = gi >> 2, cg = gi & 3;
            int cgs = cg ^ ((row >> 1) & 3);
            gload16(&Bbase[(long)(col0 + row) * ldb + k0 + cgs * 8], &Bb[c][gi * 8]);
        }
    };

    STAGE(0, 0);
    STAGE(1, 1);

    int cbr = (g ^ ((l15 >> 1) & 3)) * 16;

    int cur = 0;
    for (int T = 0; T < NT; ++T) {
        if (T + 1 < NT) { VMCNT(3); } else { VMCNT(0); }
        __builtin_amdgcn_s_barrier();
        asm volatile("" ::: "memory");

        const char* Ab_ = (const char*)&Ab[cur][0];
        const char* Bb_ = (const char*)&Bb[cur][0];
        bf16x8 af[4], bfr[2];
#pragma unroll
        for (int mi = 0; mi < 4; ++mi)
            af[mi] = *(const bf16x8*)(Ab_ + (wr * 64 + mi * 16 + l15) * 64 + cbr);
#pragma unroll
        for (int ni = 0; ni < 2; ++ni)
            bfr[ni] = *(const bf16x8*)(Bb_ + (wc * 32 + ni * 16 + l15) * 64 + cbr);

        if (T + 2 < NT) {
            int nxt = cur + 2;
            if (nxt >= 3) nxt -= 3;
            STAGE(nxt, T + 2);
        }

        LGKMCNT(0);
        __builtin_amdgcn_sched_barrier(0);
        __builtin_amdgcn_s_setprio(1);
#pragma unroll
        for (int mi = 0; mi < 4; ++mi)
#pragma unroll
            for (int ni = 0; ni < 2; ++ni)
                acc[mi][ni] = __builtin_amdgcn_mfma_f32_16x16x32_bf16(
                    af[mi], bfr[ni], acc[mi][ni], 0, 0, 0);
        __builtin_amdgcn_s_setprio(0);

        cur = (cur == 2) ? 0 : cur + 1;
    }

#pragma unroll
    for (int mi = 0; mi < 4; ++mi) {
#pragma unroll
        for (int ni = 0; ni < 2; ++ni) {
            int col = col0 + wc * 32 + ni * 16 + l15;
            float bv = bias ? bias[col] : 0.f;
#pragma unroll
            for (int r = 0; r < 4; ++r) {
                int row = row0 + wr * 64 + mi * 16 + g * 4 + r;
                float v = acc[mi][ni][r] + bv;
                if (act == 2) {
                    if (col < 256) {
                        C32[(long)row * ldc32 + col] = v;
                    } else {
                        v = gelu_f(v);
                        C32b[(long)row * ldc32b + (col - 256)] = v;
                        C16[(long)row * ldc16 + (col - 256)] = f2b(v);
                    }
                    continue;
                }
                if (act == 1) v = gelu_f(v);
                if (resid) v += resid[(long)bz * sR + (long)row * ldr + col];
                if (C32) C32[(long)bz * sC32 + (long)row * ldc32 + col] = v;
                if (C16) C16[(long)bz * sC16 + (long)row * ldc16 + col] = f2b(v);
            }
        }
    }
}

// ---------------------------------------------------------------------------
// Flash attention v2: 4 waves x 32 q-rows (q-tile 128), kv-tile 64.
// K double-buffered LDS via global_load_lds (counted vmcnt); V reg-staged.
// ---------------------------------------------------------------------------
template <int D>
__global__ __launch_bounds__(256, 2)
void attn_mfma(unsigned short* __restrict__ qkv, int stride, int koff, int voff, float scale)
{
    constexpr int GRL = D / 8;
    constexpr int NITK = (64 * GRL) / 256;
    constexpr int NITV = NITK;
    constexpr int NKS = D / 32;
    constexpr int NF = D / 16;
    constexpr int LV = 72;
    constexpr int LP = 72;
    constexpr int NT = NS / 64;

    __shared__ __align__(16) unsigned short Ks[2][64 * D];
    __shared__ __align__(16) unsigned short Vt[D * LV];
    __shared__ __align__(16) unsigned short Ps[128 * LP];

    int b = blockIdx.z, h = blockIdx.y, qt = blockIdx.x;
    int t = threadIdx.x, w = t >> 6, l = t & 63, l15 = l & 15, g = l >> 4;
    int wq = w * 32;
    long qbase = ((long)b * NS + qt * 128) * stride + h * D;
    long kvbase = (long)b * NS * stride + h * D;

    bf16x8 qreg[2][NKS];
#pragma unroll
    for (int qh = 0; qh < 2; ++qh)
#pragma unroll
        for (int ks = 0; ks < NKS; ++ks)
            qreg[qh][ks] = *(const bf16x8*)&qkv[qbase + (long)(wq + qh * 16 + l15) * stride + g * 8 + ks * 32];

    auto KSTAGE = [&](int c, int kt) {
#pragma unroll
        for (int i = 0; i < NITK; ++i) {
            int gi = t + i * 256;
            int row = gi / GRL, cg = gi % GRL;
            int cgs = cg ^ (row & 7);
            gload16(&qkv[kvbase + (long)(kt * 64 + row) * stride + koff + cgs * 8],
                    &Ks[c][gi * 8]);
        }
    };
    uint4 vp[NITV];
    auto VLOAD = [&](int kt) {
#pragma unroll
        for (int i = 0; i < NITV; ++i) {
            int vgi = t + i * 256;
            int kc = vgi & 63, db = vgi >> 6;
            vp[i] = *(const uint4*)&qkv[kvbase + (long)(kt * 64 + kc) * stride + voff + db * 8];
        }
    };
    auto VWRITE = [&]() {
#pragma unroll
        for (int i = 0; i < NITV; ++i) {
            int vgi = t + i * 256;
            int kc = vgi & 63, db = vgi >> 6;
            uint4 v = vp[i];
            Vt[(db * 8 + 0) * LV + kc] = (unsigned short)(v.x & 0xffff);
            Vt[(db * 8 + 1) * LV + kc] = (unsigned short)(v.x >> 16);
            Vt[(db * 8 + 2) * LV + kc] = (unsigned short)(v.y & 0xffff);
            Vt[(db * 8 + 3) * LV + kc] = (unsigned short)(v.y >> 16);
            Vt[(db * 8 + 4) * LV + kc] = (unsigned short)(v.z & 0xffff);
            Vt[(db * 8 + 5) * LV + kc] = (unsigned short)(v.z >> 16);
            Vt[(db * 8 + 6) * LV + kc] = (unsigned short)(v.w & 0xffff);
            Vt[(db * 8 + 7) * LV + kc] = (unsigned short)(v.w >> 16);
        }
    };

    KSTAGE(0, 0);
    VLOAD(0);
    KSTAGE(1, 1);
    if constexpr (NITK == 4) { VMCNT(4); } else { VMCNT(2); }
    VWRITE();
    LGKMCNT(0);
    __builtin_amdgcn_sched_barrier(0);
    __builtin_amdgcn_s_barrier();

    float m_run[2] = {-INFINITY, -INFINITY};
    float l_run[2] = {0.f, 0.f};
    f32x4 zero4 = {0.f, 0.f, 0.f, 0.f};
    f32x4 oacc[2][NF];
#pragma unroll
    for (int qh = 0; qh < 2; ++qh)
#pragma unroll
        for (int nf = 0; nf < NF; ++nf) oacc[qh][nf] = zero4;

    int xr = (l15 & 7) << 4;
    for (int kt = 0; kt < NT; ++kt) {
        if (kt + 1 < NT) VLOAD(kt + 1);

        const char* ksb = (const char*)&Ks[kt & 1][0];
        f32x4 st[4][2];
#pragma unroll
        for (int f = 0; f < 4; ++f)
#pragma unroll
            for (int qh = 0; qh < 2; ++qh) st[f][qh] = zero4;
#pragma unroll
        for (int ks = 0; ks < NKS; ++ks) {
#pragma unroll
            for (int f = 0; f < 4; ++f) {
                int cb = (g * 16 + ks * 64) ^ xr;
                bf16x8 a = *(const bf16x8*)(ksb + (f * 16 + l15) * (D * 2) + cb);
#pragma unroll
                for (int qh = 0; qh < 2; ++qh)
                    st[f][qh] = __builtin_amdgcn_mfma_f32_16x16x32_bf16(a, qreg[qh][ks], st[f][qh], 0, 0, 0);
            }
        }
#pragma unroll
        for (int qh = 0; qh < 2; ++qh) {
            float pm = -INFINITY;
#pragma unroll
            for (int f = 0; f < 4; ++f) {
                st[f][qh] *= scale;
#pragma unroll
                for (int r = 0; r < 4; ++r) pm = fmaxf(pm, st[f][qh][r]);
            }
            pm = fmaxf(pm, __shfl_xor(pm, 16));
            pm = fmaxf(pm, __shfl_xor(pm, 32));
            float mn = fmaxf(m_run[qh], pm);
            float corr = __expf(m_run[qh] - mn);
            float rs = 0.f;
#pragma unroll
            for (int f = 0; f < 4; ++f) {
                float p0 = __expf(st[f][qh][0] - mn);
                float p1 = __expf(st[f][qh][1] - mn);
                float p2 = __expf(st[f][qh][2] - mn);
                float p3 = __expf(st[f][qh][3] - mn);
                rs += (p0 + p1) + (p2 + p3);
                ushort4 pw;
                pw.x = f2b(p0); pw.y = f2b(p1); pw.z = f2b(p2); pw.w = f2b(p3);
                *(ushort4*)&Ps[(wq + qh * 16 + l15) * LP + f * 16 + g * 4] = pw;
            }
            rs += __shfl_xor(rs, 16);
            rs += __shfl_xor(rs, 32);
            l_run[qh] = l_run[qh] * corr + rs;
            m_run[qh] = mn;
            float corrO[4];
#pragma unroll
            for (int r = 0; r < 4; ++r) corrO[r] = __shfl(corr, g * 4 + r);
#pragma unroll
            for (int nf = 0; nf < NF; ++nf)
#pragma unroll
                for (int r = 0; r < 4; ++r) oacc[qh][nf][r] *= corrO[r];
        }
#pragma unroll
        for (int ks2 = 0; ks2 < 2; ++ks2) {
            bf16x8 vb[NF];
#pragma unroll
            for (int nf = 0; nf < NF; ++nf)
                vb[nf] = *(const bf16x8*)&Vt[(nf * 16 + l15) * LV + ks2 * 32 + g * 8];
#pragma unroll
            for (int qh = 0; qh < 2; ++qh) {
                bf16x8 pa = *(const bf16x8*)&Ps[(wq + qh * 16 + l15) * LP + ks2 * 32 + g * 8];
#pragma unroll
                for (int nf = 0; nf < NF; ++nf)
                    oacc[qh][nf] = __builtin_amdgcn_mfma_f32_16x16x32_bf16(pa, vb[nf], oacc[qh][nf], 0, 0, 0);
            }
        }

        if (kt + 1 < NT) {
            LGKMCNT(0);
            __builtin_amdgcn_sched_barrier(0);
            __builtin_amdgcn_s_barrier();
            if (kt + 2 < NT) {
                KSTAGE(kt & 1, kt + 2);
                if constexpr (NITK == 4) { VMCNT(4); } else { VMCNT(2); }
            } else {
                VMCNT(0);
            }
            VWRITE();
            LGKMCNT(0);
            __builtin_amdgcn_sched_barrier(0);
            __builtin_amdgcn_s_barrier();
        }
    }

#pragma unroll
    for (int qh = 0; qh < 2; ++qh) {
        float lo[4];
#pragma unroll
        for (int r = 0; r < 4; ++r) lo[r] = __shfl(l_run[qh], g * 4 + r);
#pragma unroll
        for (int nf = 0; nf < NF; ++nf)
#pragma unroll
            for (int r = 0; r < 4; ++r) {
                float o = oacc[qh][nf][r] / lo[r];
                qkv[qbase + (long)(wq + qh * 16 + g * 4 + r) * stride + nf * 16 + l15] = f2b(o);
            }
    }
}

// ---------------------------------------------------------------------------
__global__ __launch_bounds__(256)
void maxpart_aff_kernel(const float* __restrict__ aff, float* __restrict__ part)
{
    int sc = blockIdx.x, b = blockIdx.y, t = threadIdx.x;
    float m = -INFINITY;
    for (int s = sc * 32; s < (sc + 1) * 32; ++s)
        m = fmaxf(m, aff[((long)b * NS + s) * NIN + t]);
    part[(b * 32 + sc) * NIN + t] = m;
}

__global__ __launch_bounds__(256)
void rank_input_kernel(const float* __restrict__ part, int* __restrict__ idx_out,
                       float* __restrict__ w_out)
{
    int b = blockIdx.x, t = threadIdx.x;
    __shared__ float lg[256], rv[256];
    float m = part[(b * 32) * NIN + t];
#pragma unroll
    for (int sc = 1; sc < 32; ++sc) m = fmaxf(m, part[(b * 32 + sc) * NIN + t]);
    float l = m * 0.5f;
    lg[t] = l;
    rv[t] = l;
    __syncthreads();
    for (int off = 128; off; off >>= 1) {
        if (t < off) rv[t] = fmaxf(rv[t], rv[t + off]);
        __syncthreads();
    }
    float mx = rv[0];
    __syncthreads();
    float e = expf(l - mx);
    rv[t] = e;
    __syncthreads();
    for (int off = 128; off; off >>= 1) {
        if (t < off) rv[t] += rv[t + off];
        __syncthreads();
    }
    float Zs = rv[0];
    float soft = e / Zs;
    __syncthreads();
    int rank = 0;
    for (int j = 0; j < 256; ++j) {
        float vj = lg[j];
        rank += (vj > l) || (vj == l && j < t);
    }
    rv[t] = (rank < KIN) ? soft : 0.f;
    __syncthreads();
    for (int off = 128; off; off >>= 1) {
        if (t < off) rv[t] += rv[t + off];
        __syncthreads();
    }
    float msum = rv[0];
    if (rank < KIN) {
        idx_out[b * KIN + rank] = t;
        w_out[b * KIN + rank] = soft / (msum + 1e-8f);
    }
}

__global__ __launch_bounds__(512)
void rank_proc_kernel(const float* __restrict__ finals, int* __restrict__ pidx)
{
    int b = blockIdx.x, t = threadIdx.x;
    __shared__ float v[512];
    float xv = finals[b * NPROC + t];
    v[t] = xv;
    __syncthreads();
    int rank = 0;
    for (int j = 0; j < 512; ++j) {
        float vj = v[j];
        rank += (vj > xv) || (vj == xv && j < t);
    }
    if (rank < KPROC) pidx[b * KPROC + rank] = t;
}

// ---------------------------------------------------------------------------
// LN + routed gather, wave-per-row. Block = 4 waves = 4 rows; grid = 2048.
// ---------------------------------------------------------------------------
__global__ __launch_bounds__(256)
void ln_gather_kernel(const float* __restrict__ a, const unsigned short* __restrict__ bsrc,
                      const float* __restrict__ gg, const float* __restrict__ be,
                      const int* __restrict__ idx_in, const float* __restrict__ w_sel,
                      unsigned short* __restrict__ sel_acts)
{
    int w = threadIdx.x >> 6, l = threadIdx.x & 63;
    long row = (long)blockIdx.x * 4 + w;
    int b = (int)(row >> 10);
    __shared__ float lnv[4][256];

    float4 av = *(const float4*)&a[row * 256 + l * 4];
    ushort4 bu = *(const ushort4*)&bsrc[row * 256 + l * 4];
    float v0 = av.x + b2f(bu.x);
    float v1 = av.y + b2f(bu.y);
    float v2 = av.z + b2f(bu.z);
    float v3 = av.w + b2f(bu.w);
    float s = (v0 + v1) + (v2 + v3);
#pragma unroll
    for (int off = 1; off < 64; off <<= 1) s += __shfl_xor(s, off);
    float mean = s * (1.f / 256.f);
    float d0 = v0 - mean, d1 = v1 - mean, d2 = v2 - mean, d3 = v3 - mean;
    float ss = (d0 * d0 + d1 * d1) + (d2 * d2 + d3 * d3);
#pragma unroll
    for (int off = 1; off < 64; off <<= 1) ss += __shfl_xor(ss, off);
    float rstd = rsqrtf(ss * (1.f / 256.f) + 1e-5f);
    float4 gv = *(const float4*)&gg[l * 4];
    float4 bev = *(const float4*)&be[l * 4];
    lnv[w][l * 4 + 0] = d0 * rstd * gv.x + bev.x;
    lnv[w][l * 4 + 1] = d1 * rstd * gv.y + bev.y;
    lnv[w][l * 4 + 2] = d2 * rstd * gv.z + bev.z;
    lnv[w][l * 4 + 3] = d3 * rstd * gv.w + bev.w;
    int id0 = idx_in[b * KIN + l];
    int id1 = idx_in[b * KIN + l + 64];
    sel_acts[row * KIN + l] = f2b(lnv[w][id0] * w_sel[b * KIN + l]);
    sel_acts[row * KIN + l + 64] = f2b(lnv[w][id1] * w_sel[b * KIN + l + 64]);
}

__global__ void gather_sel_cw_b(const float* __restrict__ comb_w, const int* __restrict__ idx_in,
                                unsigned short* __restrict__ sel_cw)
{
    int gidx = blockIdx.x * 256 + threadIdx.x;
    int b = gidx >> 16;
    int rem = gidx & 65535;
    int pb = rem >> 7, j = rem & 127;
    sel_cw[gidx] = f2b(comb_w[pb * NIN + idx_in[b * KIN + j]]);
}

__global__ void gather_sel_proc_b(const unsigned short* __restrict__ proc_acts,
                                  const int* __restrict__ pidx,
                                  unsigned short* __restrict__ sel_proc)
{
    int s = blockIdx.x, b = blockIdx.y, j = threadIdx.x;
    long row = (long)b * NS + s;
    sel_proc[row * KPROC + j] = proc_acts[row * NPROC + pidx[b * KPROC + j]];
}

__global__ void gather_sel_projT(const float* __restrict__ out_proj_w, const int* __restrict__ pidx,
                                 unsigned short* __restrict__ selT)
{
    int gidx = blockIdx.x * 256 + threadIdx.x;
    int b = gidx >> 15;
    int rem = gidx & 32767;
    int d = rem >> 5;
    int kp0 = (rem & 31) * 8;
    unsigned int u[4];
#pragma unroll
    for (int i = 0; i < 4; ++i) {
        unsigned short e0 = f2b(out_proj_w[(long)pidx[b * KPROC + kp0 + 2 * i] * ND + d]);
        unsigned short e1 = f2b(out_proj_w[(long)pidx[b * KPROC + kp0 + 2 * i + 1] * ND + d]);
        u[i] = (unsigned int)e0 | ((unsigned int)e1 << 16);
    }
    uint4 o; o.x = u[0]; o.y = u[1]; o.z = u[2]; o.w = u[3];
    *(uint4*)&selT[((long)b * ND + d) * KPROC + kp0] = o;
}

__global__ __launch_bounds__(512)
void maxpart_kernel(const unsigned short* __restrict__ proc, float* __restrict__ part)
{
    int sc = blockIdx.x, b = blockIdx.y, t = threadIdx.x;
    float m = -INFINITY;
    for (int s = sc * 32; s < (sc + 1) * 32; ++s)
        m = fmaxf(m, b2f(proc[((long)b * NS + s) * NPROC + t]));
    part[(b * 32 + sc) * NPROC + t] = m;
}

// ---------------------------------------------------------------------------
// relevance split: rel1 then finals (wave-per-p, coalesced a2)
// ---------------------------------------------------------------------------
__global__ __launch_bounds__(512)
void rel1_kernel(const int* __restrict__ idx_in, const float* __restrict__ a1w,
                 const float* __restrict__ a1b, float* __restrict__ rel1g)
{
    int b = blockIdx.x, t = threadIdx.x;
    __shared__ int sidx[KIN];
    if (t < KIN) sidx[t] = idx_in[b * KIN + t];
    __syncthreads();
    float r1 = a1b[t];
    const float* a1row = a1w + (long)t * NIN;
    for (int j = 0; j < KIN; ++j) r1 += a1row[sidx[j]];
    rel1g[b * 512 + t] = gelu_f(r1);
}

__global__ __launch_bounds__(256)
void finals_kernel(const float* __restrict__ maxpart, const float* __restrict__ rel1g,
                   const float* __restrict__ a2w, const float* __restrict__ a2b,
                   float* __restrict__ finals)
{
    int b = blockIdx.y;
    int w = threadIdx.x >> 6, l = threadIdx.x & 63;
    __shared__ float r1[512];
    for (int i = threadIdx.x; i < 512; i += 256) r1[i] = rel1g[b * 512 + i];
    __syncthreads();
#pragma unroll 1
    for (int pi = 0; pi < 16; ++pi) {
        int p = blockIdx.x * 64 + w * 16 + pi;
        const float* a2row = a2w + (long)p * 512;
        float acc = 0.f;
#pragma unroll
        for (int i = 0; i < 8; ++i)
            acc += a2row[l + i * 64] * r1[l + i * 64];
#pragma unroll
        for (int off = 1; off < 64; off <<= 1) acc += __shfl_xor(acc, off);
        float m = (l < 32) ? maxpart[((long)b * 32 + l) * NPROC + p] : -INFINITY;
#pragma unroll
        for (int off = 1; off < 32; off <<= 1) m = fmaxf(m, __shfl_xor(m, off));
        if (l == 0) {
            float r = acc + a2b[p];
            float sig = 1.f / (1.f + expf(-r));
            finals[b * NPROC + p] = m * sig;
        }
    }
}

// ---------------------------------------------------------------------------
extern "C" void kernel_launch(void* const* d_in, const int* in_sizes, int n_in,
                              void* d_out, int out_size, void* d_ws, size_t ws_size,
                              hipStream_t stream)
{
    const float* x       = (const float*)d_in[0];
    const float* r_in_w  = (const float*)d_in[1];
    const float* r_in_b  = (const float*)d_in[2];
    const float* r_out_w = (const float*)d_in[3];
    const float* r_out_b = (const float*)d_in[4];
    const float* aff_w   = (const float*)d_in[5];
    const float* aff_b   = (const float*)d_in[6];
    const float* patterns= (const float*)d_in[7];
    const float* i_in_w  = (const float*)d_in[8];
    const float* i_in_b  = (const float*)d_in[9];
    const float* i_out_w = (const float*)d_in[10];
    const float* i_out_b = (const float*)d_in[11];
    const float* ln_g    = (const float*)d_in[12];
    const float* ln_b    = (const float*)d_in[13];
    const float* comb_w  = (const float*)d_in[14];
    const float* out_proj_w = (const float*)d_in[15];
    const float* a1w     = (const float*)d_in[16];
    const float* a1b     = (const float*)d_in[17];
    const float* a2w     = (const float*)d_in[18];
    const float* a2b     = (const float*)d_in[19];
    float* out = (float*)d_out;

    char* ws = (char*)d_ws;
    unsigned short* qkv1b    = (unsigned short*)(ws + 0);
    unsigned short* contextb = (unsigned short*)(ws + 50331648);
    unsigned short* xb       = (unsigned short*)(ws + 67108864);
    unsigned short* w_rin_b  = (unsigned short*)(ws + 83886080);
    unsigned short* w_rout_b = (unsigned short*)(ws + 90177536);
    unsigned short* w_aff_b  = (unsigned short*)(ws + 92274688);
    unsigned short* patt_b   = (unsigned short*)(ws + 92798976);
    unsigned short* w_iin_b  = (unsigned short*)(ws + 93323264);
    unsigned short* w_iout_b = (unsigned short*)(ws + 93716480);
    float* w_sel   = (float*)(ws + 93855744);
    int*   idx_in  = (int*)(ws + 93859840);
    float* finals  = (float*)(ws + 93863936);
    int*   pidx    = (int*)(ws + 93880320);
    float* affin   = (float*)(ws + 94019584);
    float* acts0   = (float*)(ws + 102408192);
    unsigned short* acts0b = (unsigned short*)(ws + 110796800);
    unsigned short* qkv2b  = (unsigned short*)(ws + 114991104);
    unsigned short* attn2projb = (unsigned short*)(ws + 0);
    unsigned short* proc_actsb = (unsigned short*)(ws + 16777216);
    unsigned short* sel_actsb = (unsigned short*)(ws + 33554432);
    unsigned short* sel_cwb   = (unsigned short*)(ws + 35651584);
    unsigned short* sel_procb = (unsigned short*)(ws + 36700160);
    unsigned short* sel_projT = (unsigned short*)(ws + 40894464);
    float* biascat  = (float*)(ws + 45088768);
    float* part_aff = (float*)(ws + 45091840);
    float* maxpart  = (float*)(ws + 45353984);
    float* rel1g    = (float*)(ws + 45878272);

    // 0. all conversions + biascat init in one launch
    cvt_all_kernel<<<2048, 256, 0, stream>>>(
        x, r_in_w, r_out_w, aff_w, patterns, i_in_w, i_out_w, aff_b,
        xb, w_rin_b, w_rout_b, w_aff_b, patt_b, w_iin_b, w_iout_b, biascat);

    // 1. qkv1 = x @ r_in_w^T + b (1536 blocks)
    gemm128s<<<1536, 256, 0, stream>>>(xb, ND, w_rin_b, ND, r_in_b, qkv1b, 3 * ND, ND, 24);
    // 2. MHA-1
    attn_mfma<128><<<dim3(8, 8, 8), 256, 0, stream>>>(qkv1b, 3 * ND, ND, 2 * ND, 0.088388347648318447f);
    // 3. context (128x128 tile, 512 blocks: 16 MFMA per 4 gloads vs 8 per 3)
    gemm128s<<<512, 256, 0, stream>>>(qkv1b, 3 * ND, w_rout_b, ND, r_out_b, contextb, ND, ND, 8);
    // 4. fused affinity+patterns (split epilogue, 512 blocks)
    gemm128e<<<dim3(512, 1, 1), 256, 0, stream>>>(
        contextb, 0, ND, w_aff_b, 0, ND, biascat, nullptr, 0, 0,
        affin, 0, NIN, acts0b, 0, NIN, acts0, NIN, ND, 8, 2);
    // 5. routing
    maxpart_aff_kernel<<<dim3(32, NB), 256, 0, stream>>>(affin, part_aff);
    rank_input_kernel<<<NB, 256, 0, stream>>>(part_aff, idx_in, w_sel);
    // 6. qkv2 (128x128 tile, 384 blocks)
    gemm128s<<<384, 256, 0, stream>>>(acts0b, NIN, w_iin_b, NIN, i_in_b, qkv2b, 3 * NIN, NIN, 6);
    // 7. MHA-2
    attn_mfma<64><<<dim3(8, 4, 8), 256, 0, stream>>>(qkv2b, 3 * NIN, NIN, 2 * NIN, 0.125f);
    // 8. attn2 out-proj -> bf16 (256 blocks; N=128-tile would under-fill grid)
    gemm128e<<<dim3(256, 1, 1), 256, 0, stream>>>(
        qkv2b, 0, 3 * NIN, w_iout_b, 0, NIN, i_out_b, nullptr, 0, 0,
        nullptr, 0, 0, attn2projb, 0, NIN, nullptr, 0, NIN, 4, 0);
    // 9. LN + routed gather (wave-per-row, 2048 blocks)
    ln_gather_kernel<<<2048, 256, 0, stream>>>(acts0, attn2projb, ln_g, ln_b,
                                               idx_in, w_sel, sel_actsb);
    gather_sel_cw_b<<<2048, 256, 0, stream>>>(comb_w, idx_in, sel_cwb);
    // 10. proc_acts -> bf16 (batched, 64 x 8)
    gemm128e<<<dim3(64, 1, NB), 256, 0, stream>>>(
        sel_actsb, (long)NS * KIN, KIN, sel_cwb, (long)NPROC * KIN, KIN,
        nullptr, nullptr, 0, 0,
        nullptr, 0, 0, proc_actsb, (long)NS * NPROC, NPROC, nullptr, 0, KIN, 8, 1);
    // 11. final scores + top-256
    maxpart_kernel<<<dim3(32, NB), 512, 0, stream>>>(proc_actsb, maxpart);
    rel1_kernel<<<NB, 512, 0, stream>>>(idx_in, a1w, a1b, rel1g);
    finals_kernel<<<dim3(8, NB), 256, 0, stream>>>(maxpart, rel1g, a2w, a2b, finals);
    rank_proc_kernel<<<NB, 512, 0, stream>>>(finals, pidx);
    // 12. output gathers + GEMM + residual (batched, 128 x 8)
    gather_sel_proc_b<<<dim3(NS, NB), KPROC, 0, stream>>>(proc_actsb, pidx, sel_procb);
    gather_sel_projT<<<1024, 256, 0, stream>>>(out_proj_w, pidx, sel_projT);
    gemm128e<<<dim3(128, 1, NB), 256, 0, stream>>>(
        sel_procb, (long)NS * KPROC, KPROC, sel_projT, (long)ND * KPROC, KPROC,
        nullptr, x, (long)NS * ND, ND,
        out, (long)NS * ND, ND, nullptr, 0, 0, nullptr, 0, KPROC, 16, 0);
    (void)in_sizes; (void)n_in; (void)out_size; (void)ws_size;
}

// Round 26
// 396.631 us; speedup vs baseline: 1.1260x; 1.0064x over previous
//
#include <hip/hip_runtime.h>
#include <hip/hip_bf16.h>
#include <math.h>

constexpr int NB = 8, NS = 1024, ND = 1024, NIN = 256, NPROC = 512, KIN = 128, KPROC = 256;

typedef __attribute__((ext_vector_type(8))) short bf16x8;
typedef __attribute__((ext_vector_type(4))) float f32x4;

#define VMCNT(n) asm volatile("s_waitcnt vmcnt(" #n ")" ::: "memory")
#define LGKMCNT(n) asm volatile("s_waitcnt lgkmcnt(" #n ")" ::: "memory")

__device__ inline float gelu_f(float x) {
    return 0.5f * x * (1.0f + erff(x * 0.7071067811865476f));
}
__device__ inline unsigned short f2b(float f) {
    __hip_bfloat16 h = __float2bfloat16(f);
    return *reinterpret_cast<unsigned short*>(&h);
}
__device__ inline float b2f(unsigned short u) {
    unsigned int v = (unsigned int)u << 16;
    return __uint_as_float(v);
}
__device__ inline void gload16(const void* g, void* l) {
    __builtin_amdgcn_global_load_lds(
        (const __attribute__((address_space(1))) void*)g,
        (__attribute__((address_space(3))) void*)l, 16, 0, 0);
}

// ---------------------------------------------------------------------------
// Fused f32->bf16 conversions + biascat init.
// ---------------------------------------------------------------------------
__global__ __launch_bounds__(256)
void cvt_all_kernel(const float* __restrict__ x, const float* __restrict__ rin,
                    const float* __restrict__ rout, const float* __restrict__ affw,
                    const float* __restrict__ patt, const float* __restrict__ iin,
                    const float* __restrict__ iout, const float* __restrict__ aff_b,
                    unsigned short* __restrict__ xb, unsigned short* __restrict__ rinb,
                    unsigned short* __restrict__ routb, unsigned short* __restrict__ affbw,
                    unsigned short* __restrict__ pattb, unsigned short* __restrict__ iinb,
                    unsigned short* __restrict__ ioutb, float* __restrict__ biascat)
{
    if (blockIdx.x == 0) {
        int t = threadIdx.x;
        biascat[t] = aff_b[t];
        biascat[256 + t] = 0.f;
    }
    long gi = (long)blockIdx.x * 256 + threadIdx.x;
    long stride = (long)gridDim.x * 256;
    for (; gi < 3342336; gi += stride) {
        const float4* s; ushort4* d; long off;
        if (gi < 2097152)      { s = (const float4*)x;    d = (ushort4*)xb;    off = gi; }
        else if (gi < 2883584) { s = (const float4*)rin;  d = (ushort4*)rinb;  off = gi - 2097152; }
        else if (gi < 3145728) { s = (const float4*)rout; d = (ushort4*)routb; off = gi - 2883584; }
        else if (gi < 3211264) { s = (const float4*)affw; d = (ushort4*)affbw; off = gi - 3145728; }
        else if (gi < 3276800) { s = (const float4*)patt; d = (ushort4*)pattb; off = gi - 3211264; }
        else if (gi < 3325952) { s = (const float4*)iin;  d = (ushort4*)iinb;  off = gi - 3276800; }
        else                   { s = (const float4*)iout; d = (ushort4*)ioutb; off = gi - 3325952; }
        float4 v = s[off];
        ushort4 o;
        o.x = f2b(v.x); o.y = f2b(v.y); o.z = f2b(v.z); o.w = f2b(v.w);
        d[off] = o;
    }
}

// ---------------------------------------------------------------------------
// 128x128 bf16 MFMA GEMM, BK=32 triple-buffer, one barrier/tile, 4 waves,
// counted vmcnt + 2-bit XOR swizzle. Rectangular per-XCD block mapping:
// each XCD owns 8 row-blocks (A slice L2-resident) and walks col-bands of
// wband blocks (B band L2-resident). 48KB LDS.
// ---------------------------------------------------------------------------
__global__ __launch_bounds__(256)
void gemm128s(const unsigned short* __restrict__ A, int lda,
              const unsigned short* __restrict__ B, int ldb,
              const float* __restrict__ bias,
              unsigned short* __restrict__ C16, int ldc,
              int K, int nbx, int wband)
{
    __shared__ __align__(16) unsigned short Ab[3][128 * 32];
    __shared__ __align__(16) unsigned short Bb[3][128 * 32];
    int o = blockIdx.x;
    int xcd = o & 7, local = o >> 3;
    int R = (int)(gridDim.x / nbx) >> 3;     // row-blocks per XCD
    int bw = R * wband;
    int band = local / bw, rem = local - band * bw;
    int lr = rem / wband, lc = rem - lr * wband;
    int by = xcd * R + lr, bx = band * wband + lc;
    int row0 = by * 128, col0 = bx * 128;

    int t = threadIdx.x;
    int w = t >> 6, l = t & 63, l15 = l & 15, g = l >> 4;
    int wr = w >> 1, wc = w & 1;
    int NT = K >> 5;

    f32x4 acc[4][4];
#pragma unroll
    for (int i = 0; i < 4; ++i)
#pragma unroll
        for (int j = 0; j < 4; ++j) acc[i][j] = (f32x4){0.f, 0.f, 0.f, 0.f};

    auto STAGE = [&](int c, int kt) {
        int k0 = kt * 32;
#pragma unroll
        for (int i = 0; i < 2; ++i) {
            int gi = t + i * 256;
            int row = gi >> 2, cg = gi & 3;
            int cgs = cg ^ ((row >> 1) & 3);
            gload16(&A[(long)(row0 + row) * lda + k0 + cgs * 8], &Ab[c][gi * 8]);
        }
#pragma unroll
        for (int i = 0; i < 2; ++i) {
            int gi = t + i * 256;
            int row = gi >> 2, cg = gi & 3;
            int cgs = cg ^ ((row >> 1) & 3);
            gload16(&B[(long)(col0 + row) * ldb + k0 + cgs * 8], &Bb[c][gi * 8]);
        }
    };

    STAGE(0, 0);
    STAGE(1, 1);

    int cbr = (g ^ ((l15 >> 1) & 3)) * 16;

    int cur = 0;
    for (int T = 0; T < NT; ++T) {
        if (T + 1 < NT) { VMCNT(4); } else { VMCNT(0); }
        __builtin_amdgcn_s_barrier();
        asm volatile("" ::: "memory");

        const char* Ab_ = (const char*)&Ab[cur][0];
        const char* Bb_ = (const char*)&Bb[cur][0];
        bf16x8 af[4], bfr[4];
#pragma unroll
        for (int mi = 0; mi < 4; ++mi)
            af[mi] = *(const bf16x8*)(Ab_ + (wr * 64 + mi * 16 + l15) * 64 + cbr);
#pragma unroll
        for (int ni = 0; ni < 4; ++ni)
            bfr[ni] = *(const bf16x8*)(Bb_ + (wc * 64 + ni * 16 + l15) * 64 + cbr);

        if (T + 2 < NT) {
            int nxt = cur + 2;
            if (nxt >= 3) nxt -= 3;
            STAGE(nxt, T + 2);
        }

        LGKMCNT(0);
        __builtin_amdgcn_sched_barrier(0);
        __builtin_amdgcn_s_setprio(1);
#pragma unroll
        for (int mi = 0; mi < 4; ++mi)
#pragma unroll
            for (int ni = 0; ni < 4; ++ni)
                acc[mi][ni] = __builtin_amdgcn_mfma_f32_16x16x32_bf16(
                    af[mi], bfr[ni], acc[mi][ni], 0, 0, 0);
        __builtin_amdgcn_s_setprio(0);

        cur = (cur == 2) ? 0 : cur + 1;
    }

#pragma unroll
    for (int mi = 0; mi < 4; ++mi) {
#pragma unroll
        for (int ni = 0; ni < 4; ++ni) {
            int col = col0 + wc * 64 + ni * 16 + l15;
            float bv = bias ? bias[col] : 0.f;
#pragma unroll
            for (int r = 0; r < 4; ++r) {
                int row = row0 + wr * 64 + mi * 16 + g * 4 + r;
                float v = acc[mi][ni][r] + bv;
                float vp = __shfl_xor(v, 1);
                if (!(l15 & 1)) {
                    unsigned int u = (unsigned int)f2b(v) | ((unsigned int)f2b(vp) << 16);
                    *(unsigned int*)&C16[(long)row * ldc + col] = u;
                }
            }
        }
    }
}

// ---------------------------------------------------------------------------
// gemm128e: 128x64 triple-buffer pipeline + full epilogue + batch (z).
// act: 0 plain (+resid opt), 1 gelu, 2 split@256.
// ---------------------------------------------------------------------------
__global__ __launch_bounds__(256)
void gemm128e(const unsigned short* __restrict__ A, long sA, int lda,
              const unsigned short* __restrict__ B, long sB, int ldb,
              const float* __restrict__ bias,
              const float* __restrict__ resid, long sR, int ldr,
              float* __restrict__ C32, long sC32, int ldc32,
              unsigned short* __restrict__ C16, long sC16, int ldc16,
              float* __restrict__ C32b, int ldc32b,
              int K, int nbx, int act)
{
    __shared__ __align__(16) unsigned short Ab[3][128 * 32];
    __shared__ __align__(16) unsigned short Bb[3][64 * 32];
    int bz = blockIdx.z;
    const unsigned short* Abase = A + (long)bz * sA;
    const unsigned short* Bbase = B + (long)bz * sB;
    int o = blockIdx.x;
    int cpx = gridDim.x >> 3;
    int swz = (o & 7) * cpx + (o >> 3);
    int by = swz / nbx, bx = swz - by * nbx;
    int row0 = by * 128, col0 = bx * 64;

    int t = threadIdx.x;
    int w = t >> 6, l = t & 63, l15 = l & 15, g = l >> 4;
    int wr = w >> 1, wc = w & 1;
    int NT = K >> 5;

    f32x4 acc[4][2];
#pragma unroll
    for (int i = 0; i < 4; ++i)
#pragma unroll
        for (int j = 0; j < 2; ++j) acc[i][j] = (f32x4){0.f, 0.f, 0.f, 0.f};

    auto STAGE = [&](int c, int kt) {
        int k0 = kt * 32;
#pragma unroll
        for (int i = 0; i < 2; ++i) {
            int gi = t + i * 256;
            int row = gi >> 2, cg = gi & 3;
            int cgs = cg ^ ((row >> 1) & 3);
            gload16(&Abase[(long)(row0 + row) * lda + k0 + cgs * 8], &Ab[c][gi * 8]);
        }
        {
            int gi = t;
            int row = gi >> 2, cg = gi & 3;
            int cgs = cg ^ ((row >> 1) & 3);
            gload16(&Bbase[(long)(col0 + row) * ldb + k0 + cgs * 8], &Bb[c][gi * 8]);
        }
    };

    STAGE(0, 0);
    STAGE(1, 1);

    int cbr = (g ^ ((l15 >> 1) & 3)) * 16;

    int cur = 0;
    for (int T = 0; T < NT; ++T) {
        if (T + 1 < NT) { VMCNT(3); } else { VMCNT(0); }
        __builtin_amdgcn_s_barrier();
        asm volatile("" ::: "memory");

        const char* Ab_ = (const char*)&Ab[cur][0];
        const char* Bb_ = (const char*)&Bb[cur][0];
        bf16x8 af[4], bfr[2];
#pragma unroll
        for (int mi = 0; mi < 4; ++mi)
            af[mi] = *(const bf16x8*)(Ab_ + (wr * 64 + mi * 16 + l15) * 64 + cbr);
#pragma unroll
        for (int ni = 0; ni < 2; ++ni)
            bfr[ni] = *(const bf16x8*)(Bb_ + (wc * 32 + ni * 16 + l15) * 64 + cbr);

        if (T + 2 < NT) {
            int nxt = cur + 2;
            if (nxt >= 3) nxt -= 3;
            STAGE(nxt, T + 2);
        }

        LGKMCNT(0);
        __builtin_amdgcn_sched_barrier(0);
        __builtin_amdgcn_s_setprio(1);
#pragma unroll
        for (int mi = 0; mi < 4; ++mi)
#pragma unroll
            for (int ni = 0; ni < 2; ++ni)
                acc[mi][ni] = __builtin_amdgcn_mfma_f32_16x16x32_bf16(
                    af[mi], bfr[ni], acc[mi][ni], 0, 0, 0);
        __builtin_amdgcn_s_setprio(0);

        cur = (cur == 2) ? 0 : cur + 1;
    }

#pragma unroll
    for (int mi = 0; mi < 4; ++mi) {
#pragma unroll
        for (int ni = 0; ni < 2; ++ni) {
            int col = col0 + wc * 32 + ni * 16 + l15;
            float bv = bias ? bias[col] : 0.f;
#pragma unroll
            for (int r = 0; r < 4; ++r) {
                int row = row0 + wr * 64 + mi * 16 + g * 4 + r;
                float v = acc[mi][ni][r] + bv;
                if (act == 2) {
                    if (col < 256) {
                        C32[(long)row * ldc32 + col] = v;
                    } else {
                        v = gelu_f(v);
                        C32b[(long)row * ldc32b + (col - 256)] = v;
                        C16[(long)row * ldc16 + (col - 256)] = f2b(v);
                    }
                    continue;
                }
                if (act == 1) v = gelu_f(v);
                if (resid) v += resid[(long)bz * sR + (long)row * ldr + col];
                if (C32) C32[(long)bz * sC32 + (long)row * ldc32 + col] = v;
                if (C16) C16[(long)bz * sC16 + (long)row * ldc16 + col] = f2b(v);
            }
        }
    }
}

// ---------------------------------------------------------------------------
// Flash attention v2: 4 waves x 32 q-rows (q-tile 128), kv-tile 64.
// K double-buffered LDS via global_load_lds (counted vmcnt); V reg-staged.
// ---------------------------------------------------------------------------
template <int D>
__global__ __launch_bounds__(256, 2)
void attn_mfma(unsigned short* __restrict__ qkv, int stride, int koff, int voff, float scale)
{
    constexpr int GRL = D / 8;
    constexpr int NITK = (64 * GRL) / 256;
    constexpr int NITV = NITK;
    constexpr int NKS = D / 32;
    constexpr int NF = D / 16;
    constexpr int LV = 72;
    constexpr int LP = 72;
    constexpr int NT = NS / 64;

    __shared__ __align__(16) unsigned short Ks[2][64 * D];
    __shared__ __align__(16) unsigned short Vt[D * LV];
    __shared__ __align__(16) unsigned short Ps[128 * LP];

    int b = blockIdx.z, h = blockIdx.y, qt = blockIdx.x;
    int t = threadIdx.x, w = t >> 6, l = t & 63, l15 = l & 15, g = l >> 4;
    int wq = w * 32;
    long qbase = ((long)b * NS + qt * 128) * stride + h * D;
    long kvbase = (long)b * NS * stride + h * D;

    bf16x8 qreg[2][NKS];
#pragma unroll
    for (int qh = 0; qh < 2; ++qh)
#pragma unroll
        for (int ks = 0; ks < NKS; ++ks)
            qreg[qh][ks] = *(const bf16x8*)&qkv[qbase + (long)(wq + qh * 16 + l15) * stride + g * 8 + ks * 32];

    auto KSTAGE = [&](int c, int kt) {
#pragma unroll
        for (int i = 0; i < NITK; ++i) {
            int gi = t + i * 256;
            int row = gi / GRL, cg = gi % GRL;
            int cgs = cg ^ (row & 7);
            gload16(&qkv[kvbase + (long)(kt * 64 + row) * stride + koff + cgs * 8],
                    &Ks[c][gi * 8]);
        }
    };
    uint4 vp[NITV];
    auto VLOAD = [&](int kt) {
#pragma unroll
        for (int i = 0; i < NITV; ++i) {
            int vgi = t + i * 256;
            int kc = vgi & 63, db = vgi >> 6;
            vp[i] = *(const uint4*)&qkv[kvbase + (long)(kt * 64 + kc) * stride + voff + db * 8];
        }
    };
    auto VWRITE = [&]() {
#pragma unroll
        for (int i = 0; i < NITV; ++i) {
            int vgi = t + i * 256;
            int kc = vgi & 63, db = vgi >> 6;
            uint4 v = vp[i];
            Vt[(db * 8 + 0) * LV + kc] = (unsigned short)(v.x & 0xffff);
            Vt[(db * 8 + 1) * LV + kc] = (unsigned short)(v.x >> 16);
            Vt[(db * 8 + 2) * LV + kc] = (unsigned short)(v.y & 0xffff);
            Vt[(db * 8 + 3) * LV + kc] = (unsigned short)(v.y >> 16);
            Vt[(db * 8 + 4) * LV + kc] = (unsigned short)(v.z & 0xffff);
            Vt[(db * 8 + 5) * LV + kc] = (unsigned short)(v.z >> 16);
            Vt[(db * 8 + 6) * LV + kc] = (unsigned short)(v.w & 0xffff);
            Vt[(db * 8 + 7) * LV + kc] = (unsigned short)(v.w >> 16);
        }
    };

    KSTAGE(0, 0);
    VLOAD(0);
    KSTAGE(1, 1);
    if constexpr (NITK == 4) { VMCNT(4); } else { VMCNT(2); }
    VWRITE();
    LGKMCNT(0);
    __builtin_amdgcn_sched_barrier(0);
    __builtin_amdgcn_s_barrier();

    float m_run[2] = {-INFINITY, -INFINITY};
    float l_run[2] = {0.f, 0.f};
    f32x4 zero4 = {0.f, 0.f, 0.f, 0.f};
    f32x4 oacc[2][NF];
#pragma unroll
    for (int qh = 0; qh < 2; ++qh)
#pragma unroll
        for (int nf = 0; nf < NF; ++nf) oacc[qh][nf] = zero4;

    int xr = (l15 & 7) << 4;
    for (int kt = 0; kt < NT; ++kt) {
        if (kt + 1 < NT) VLOAD(kt + 1);

        const char* ksb = (const char*)&Ks[kt & 1][0];
        f32x4 st[4][2];
#pragma unroll
        for (int f = 0; f < 4; ++f)
#pragma unroll
            for (int qh = 0; qh < 2; ++qh) st[f][qh] = zero4;
#pragma unroll
        for (int ks = 0; ks < NKS; ++ks) {
#pragma unroll
            for (int f = 0; f < 4; ++f) {
                int cb = (g * 16 + ks * 64) ^ xr;
                bf16x8 a = *(const bf16x8*)(ksb + (f * 16 + l15) * (D * 2) + cb);
#pragma unroll
                for (int qh = 0; qh < 2; ++qh)
                    st[f][qh] = __builtin_amdgcn_mfma_f32_16x16x32_bf16(a, qreg[qh][ks], st[f][qh], 0, 0, 0);
            }
        }
#pragma unroll
        for (int qh = 0; qh < 2; ++qh) {
            float pm = -INFINITY;
#pragma unroll
            for (int f = 0; f < 4; ++f) {
                st[f][qh] *= scale;
#pragma unroll
                for (int r = 0; r < 4; ++r) pm = fmaxf(pm, st[f][qh][r]);
            }
            pm = fmaxf(pm, __shfl_xor(pm, 16));
            pm = fmaxf(pm, __shfl_xor(pm, 32));
            float mn = fmaxf(m_run[qh], pm);
            float corr = __expf(m_run[qh] - mn);
            float rs = 0.f;
#pragma unroll
            for (int f = 0; f < 4; ++f) {
                float p0 = __expf(st[f][qh][0] - mn);
                float p1 = __expf(st[f][qh][1] - mn);
                float p2 = __expf(st[f][qh][2] - mn);
                float p3 = __expf(st[f][qh][3] - mn);
                rs += (p0 + p1) + (p2 + p3);
                ushort4 pw;
                pw.x = f2b(p0); pw.y = f2b(p1); pw.z = f2b(p2); pw.w = f2b(p3);
                *(ushort4*)&Ps[(wq + qh * 16 + l15) * LP + f * 16 + g * 4] = pw;
            }
            rs += __shfl_xor(rs, 16);
            rs += __shfl_xor(rs, 32);
            l_run[qh] = l_run[qh] * corr + rs;
            m_run[qh] = mn;
            float corrO[4];
#pragma unroll
            for (int r = 0; r < 4; ++r) corrO[r] = __shfl(corr, g * 4 + r);
#pragma unroll
            for (int nf = 0; nf < NF; ++nf)
#pragma unroll
                for (int r = 0; r < 4; ++r) oacc[qh][nf][r] *= corrO[r];
        }
#pragma unroll
        for (int ks2 = 0; ks2 < 2; ++ks2) {
            bf16x8 vb[NF];
#pragma unroll
            for (int nf = 0; nf < NF; ++nf)
                vb[nf] = *(const bf16x8*)&Vt[(nf * 16 + l15) * LV + ks2 * 32 + g * 8];
#pragma unroll
            for (int qh = 0; qh < 2; ++qh) {
                bf16x8 pa = *(const bf16x8*)&Ps[(wq + qh * 16 + l15) * LP + ks2 * 32 + g * 8];
#pragma unroll
                for (int nf = 0; nf < NF; ++nf)
                    oacc[qh][nf] = __builtin_amdgcn_mfma_f32_16x16x32_bf16(pa, vb[nf], oacc[qh][nf], 0, 0, 0);
            }
        }

        if (kt + 1 < NT) {
            LGKMCNT(0);
            __builtin_amdgcn_sched_barrier(0);
            __builtin_amdgcn_s_barrier();
            if (kt + 2 < NT) {
                KSTAGE(kt & 1, kt + 2);
                if constexpr (NITK == 4) { VMCNT(4); } else { VMCNT(2); }
            } else {
                VMCNT(0);
            }
            VWRITE();
            LGKMCNT(0);
            __builtin_amdgcn_sched_barrier(0);
            __builtin_amdgcn_s_barrier();
        }
    }

#pragma unroll
    for (int qh = 0; qh < 2; ++qh) {
        float lo[4];
#pragma unroll
        for (int r = 0; r < 4; ++r) lo[r] = __shfl(l_run[qh], g * 4 + r);
#pragma unroll
        for (int nf = 0; nf < NF; ++nf)
#pragma unroll
            for (int r = 0; r < 4; ++r) {
                float o = oacc[qh][nf][r] / lo[r];
                qkv[qbase + (long)(wq + qh * 16 + g * 4 + r) * stride + nf * 16 + l15] = f2b(o);
            }
    }
}

// ---------------------------------------------------------------------------
__global__ __launch_bounds__(256)
void maxpart_aff_kernel(const float* __restrict__ aff, float* __restrict__ part)
{
    int sc = blockIdx.x, b = blockIdx.y, t = threadIdx.x;
    float m = -INFINITY;
    for (int s = sc * 32; s < (sc + 1) * 32; ++s)
        m = fmaxf(m, aff[((long)b * NS + s) * NIN + t]);
    part[(b * 32 + sc) * NIN + t] = m;
}

__global__ __launch_bounds__(256)
void rank_input_kernel(const float* __restrict__ part, int* __restrict__ idx_out,
                       float* __restrict__ w_out)
{
    int b = blockIdx.x, t = threadIdx.x;
    __shared__ float lg[256], rv[256];
    float m = part[(b * 32) * NIN + t];
#pragma unroll
    for (int sc = 1; sc < 32; ++sc) m = fmaxf(m, part[(b * 32 + sc) * NIN + t]);
    float l = m * 0.5f;
    lg[t] = l;
    rv[t] = l;
    __syncthreads();
    for (int off = 128; off; off >>= 1) {
        if (t < off) rv[t] = fmaxf(rv[t], rv[t + off]);
        __syncthreads();
    }
    float mx = rv[0];
    __syncthreads();
    float e = expf(l - mx);
    rv[t] = e;
    __syncthreads();
    for (int off = 128; off; off >>= 1) {
        if (t < off) rv[t] += rv[t + off];
        __syncthreads();
    }
    float Zs = rv[0];
    float soft = e / Zs;
    __syncthreads();
    int rank = 0;
    for (int j = 0; j < 256; ++j) {
        float vj = lg[j];
        rank += (vj > l) || (vj == l && j < t);
    }
    rv[t] = (rank < KIN) ? soft : 0.f;
    __syncthreads();
    for (int off = 128; off; off >>= 1) {
        if (t < off) rv[t] += rv[t + off];
        __syncthreads();
    }
    float msum = rv[0];
    if (rank < KIN) {
        idx_out[b * KIN + rank] = t;
        w_out[b * KIN + rank] = soft / (msum + 1e-8f);
    }
}

__global__ __launch_bounds__(512)
void rank_proc_kernel(const float* __restrict__ finals, int* __restrict__ pidx)
{
    int b = blockIdx.x, t = threadIdx.x;
    __shared__ float v[512];
    float xv = finals[b * NPROC + t];
    v[t] = xv;
    __syncthreads();
    int rank = 0;
    for (int j = 0; j < 512; ++j) {
        float vj = v[j];
        rank += (vj > xv) || (vj == xv && j < t);
    }
    if (rank < KPROC) pidx[b * KPROC + rank] = t;
}

// ---------------------------------------------------------------------------
// LN + routed gather, wave-per-row. Block = 4 waves = 4 rows; grid = 2048.
// ---------------------------------------------------------------------------
__global__ __launch_bounds__(256)
void ln_gather_kernel(const float* __restrict__ a, const unsigned short* __restrict__ bsrc,
                      const float* __restrict__ gg, const float* __restrict__ be,
                      const int* __restrict__ idx_in, const float* __restrict__ w_sel,
                      unsigned short* __restrict__ sel_acts)
{
    int w = threadIdx.x >> 6, l = threadIdx.x & 63;
    long row = (long)blockIdx.x * 4 + w;
    int b = (int)(row >> 10);
    __shared__ float lnv[4][256];

    float4 av = *(const float4*)&a[row * 256 + l * 4];
    ushort4 bu = *(const ushort4*)&bsrc[row * 256 + l * 4];
    float v0 = av.x + b2f(bu.x);
    float v1 = av.y + b2f(bu.y);
    float v2 = av.z + b2f(bu.z);
    float v3 = av.w + b2f(bu.w);
    float s = (v0 + v1) + (v2 + v3);
#pragma unroll
    for (int off = 1; off < 64; off <<= 1) s += __shfl_xor(s, off);
    float mean = s * (1.f / 256.f);
    float d0 = v0 - mean, d1 = v1 - mean, d2 = v2 - mean, d3 = v3 - mean;
    float ss = (d0 * d0 + d1 * d1) + (d2 * d2 + d3 * d3);
#pragma unroll
    for (int off = 1; off < 64; off <<= 1) ss += __shfl_xor(ss, off);
    float rstd = rsqrtf(ss * (1.f / 256.f) + 1e-5f);
    float4 gv = *(const float4*)&gg[l * 4];
    float4 bev = *(const float4*)&be[l * 4];
    lnv[w][l * 4 + 0] = d0 * rstd * gv.x + bev.x;
    lnv[w][l * 4 + 1] = d1 * rstd * gv.y + bev.y;
    lnv[w][l * 4 + 2] = d2 * rstd * gv.z + bev.z;
    lnv[w][l * 4 + 3] = d3 * rstd * gv.w + bev.w;
    int id0 = idx_in[b * KIN + l];
    int id1 = idx_in[b * KIN + l + 64];
    sel_acts[row * KIN + l] = f2b(lnv[w][id0] * w_sel[b * KIN + l]);
    sel_acts[row * KIN + l + 64] = f2b(lnv[w][id1] * w_sel[b * KIN + l + 64]);
}

__global__ void gather_sel_cw_b(const float* __restrict__ comb_w, const int* __restrict__ idx_in,
                                unsigned short* __restrict__ sel_cw)
{
    int gidx = blockIdx.x * 256 + threadIdx.x;
    int b = gidx >> 16;
    int rem = gidx & 65535;
    int pb = rem >> 7, j = rem & 127;
    sel_cw[gidx] = f2b(comb_w[pb * NIN + idx_in[b * KIN + j]]);
}

__global__ void gather_sel_proc_b(const unsigned short* __restrict__ proc_acts,
                                  const int* __restrict__ pidx,
                                  unsigned short* __restrict__ sel_proc)
{
    int s = blockIdx.x, b = blockIdx.y, j = threadIdx.x;
    long row = (long)b * NS + s;
    sel_proc[row * KPROC + j] = proc_acts[row * NPROC + pidx[b * KPROC + j]];
}

__global__ void gather_sel_projT(const float* __restrict__ out_proj_w, const int* __restrict__ pidx,
                                 unsigned short* __restrict__ selT)
{
    int gidx = blockIdx.x * 256 + threadIdx.x;
    int b = gidx >> 15;
    int rem = gidx & 32767;
    int d = rem >> 5;
    int kp0 = (rem & 31) * 8;
    unsigned int u[4];
#pragma unroll
    for (int i = 0; i < 4; ++i) {
        unsigned short e0 = f2b(out_proj_w[(long)pidx[b * KPROC + kp0 + 2 * i] * ND + d]);
        unsigned short e1 = f2b(out_proj_w[(long)pidx[b * KPROC + kp0 + 2 * i + 1] * ND + d]);
        u[i] = (unsigned int)e0 | ((unsigned int)e1 << 16);
    }
    uint4 o; o.x = u[0]; o.y = u[1]; o.z = u[2]; o.w = u[3];
    *(uint4*)&selT[((long)b * ND + d) * KPROC + kp0] = o;
}

__global__ __launch_bounds__(512)
void maxpart_kernel(const unsigned short* __restrict__ proc, float* __restrict__ part)
{
    int sc = blockIdx.x, b = blockIdx.y, t = threadIdx.x;
    float m = -INFINITY;
    for (int s = sc * 32; s < (sc + 1) * 32; ++s)
        m = fmaxf(m, b2f(proc[((long)b * NS + s) * NPROC + t]));
    part[(b * 32 + sc) * NPROC + t] = m;
}

// ---------------------------------------------------------------------------
// relevance split: rel1 then finals (wave-per-p, coalesced a2)
// ---------------------------------------------------------------------------
__global__ __launch_bounds__(512)
void rel1_kernel(const int* __restrict__ idx_in, const float* __restrict__ a1w,
                 const float* __restrict__ a1b, float* __restrict__ rel1g)
{
    int b = blockIdx.x, t = threadIdx.x;
    __shared__ int sidx[KIN];
    if (t < KIN) sidx[t] = idx_in[b * KIN + t];
    __syncthreads();
    float r1 = a1b[t];
    const float* a1row = a1w + (long)t * NIN;
    for (int j = 0; j < KIN; ++j) r1 += a1row[sidx[j]];
    rel1g[b * 512 + t] = gelu_f(r1);
}

__global__ __launch_bounds__(256)
void finals_kernel(const float* __restrict__ maxpart, const float* __restrict__ rel1g,
                   const float* __restrict__ a2w, const float* __restrict__ a2b,
                   float* __restrict__ finals)
{
    int b = blockIdx.y;
    int w = threadIdx.x >> 6, l = threadIdx.x & 63;
    __shared__ float r1[512];
    for (int i = threadIdx.x; i < 512; i += 256) r1[i] = rel1g[b * 512 + i];
    __syncthreads();
#pragma unroll 1
    for (int pi = 0; pi < 16; ++pi) {
        int p = blockIdx.x * 64 + w * 16 + pi;
        const float* a2row = a2w + (long)p * 512;
        float acc = 0.f;
#pragma unroll
        for (int i = 0; i < 8; ++i)
            acc += a2row[l + i * 64] * r1[l + i * 64];
#pragma unroll
        for (int off = 1; off < 64; off <<= 1) acc += __shfl_xor(acc, off);
        float m = (l < 32) ? maxpart[((long)b * 32 + l) * NPROC + p] : -INFINITY;
#pragma unroll
        for (int off = 1; off < 32; off <<= 1) m = fmaxf(m, __shfl_xor(m, off));
        if (l == 0) {
            float r = acc + a2b[p];
            float sig = 1.f / (1.f + expf(-r));
            finals[b * NPROC + p] = m * sig;
        }
    }
}

// ---------------------------------------------------------------------------
extern "C" void kernel_launch(void* const* d_in, const int* in_sizes, int n_in,
                              void* d_out, int out_size, void* d_ws, size_t ws_size,
                              hipStream_t stream)
{
    const float* x       = (const float*)d_in[0];
    const float* r_in_w  = (const float*)d_in[1];
    const float* r_in_b  = (const float*)d_in[2];
    const float* r_out_w = (const float*)d_in[3];
    const float* r_out_b = (const float*)d_in[4];
    const float* aff_w   = (const float*)d_in[5];
    const float* aff_b   = (const float*)d_in[6];
    const float* patterns= (const float*)d_in[7];
    const float* i_in_w  = (const float*)d_in[8];
    const float* i_in_b  = (const float*)d_in[9];
    const float* i_out_w = (const float*)d_in[10];
    const float* i_out_b = (const float*)d_in[11];
    const float* ln_g    = (const float*)d_in[12];
    const float* ln_b    = (const float*)d_in[13];
    const float* comb_w  = (const float*)d_in[14];
    const float* out_proj_w = (const float*)d_in[15];
    const float* a1w     = (const float*)d_in[16];
    const float* a1b     = (const float*)d_in[17];
    const float* a2w     = (const float*)d_in[18];
    const float* a2b     = (const float*)d_in[19];
    float* out = (float*)d_out;

    char* ws = (char*)d_ws;
    unsigned short* qkv1b    = (unsigned short*)(ws + 0);
    unsigned short* contextb = (unsigned short*)(ws + 50331648);
    unsigned short* xb       = (unsigned short*)(ws + 67108864);
    unsigned short* w_rin_b  = (unsigned short*)(ws + 83886080);
    unsigned short* w_rout_b = (unsigned short*)(ws + 90177536);
    unsigned short* w_aff_b  = (unsigned short*)(ws + 92274688);
    unsigned short* patt_b   = (unsigned short*)(ws + 92798976);
    unsigned short* w_iin_b  = (unsigned short*)(ws + 93323264);
    unsigned short* w_iout_b = (unsigned short*)(ws + 93716480);
    float* w_sel   = (float*)(ws + 93855744);
    int*   idx_in  = (int*)(ws + 93859840);
    float* finals  = (float*)(ws + 93863936);
    int*   pidx    = (int*)(ws + 93880320);
    float* affin   = (float*)(ws + 94019584);
    float* acts0   = (float*)(ws + 102408192);
    unsigned short* acts0b = (unsigned short*)(ws + 110796800);
    unsigned short* qkv2b  = (unsigned short*)(ws + 114991104);
    unsigned short* attn2projb = (unsigned short*)(ws + 0);
    unsigned short* proc_actsb = (unsigned short*)(ws + 16777216);
    unsigned short* sel_actsb = (unsigned short*)(ws + 33554432);
    unsigned short* sel_cwb   = (unsigned short*)(ws + 35651584);
    unsigned short* sel_procb = (unsigned short*)(ws + 36700160);
    unsigned short* sel_projT = (unsigned short*)(ws + 40894464);
    float* biascat  = (float*)(ws + 45088768);
    float* part_aff = (float*)(ws + 45091840);
    float* maxpart  = (float*)(ws + 45353984);
    float* rel1g    = (float*)(ws + 45878272);

    // 0. all conversions + biascat init in one launch
    cvt_all_kernel<<<2048, 256, 0, stream>>>(
        x, r_in_w, r_out_w, aff_w, patterns, i_in_w, i_out_w, aff_b,
        xb, w_rin_b, w_rout_b, w_aff_b, patt_b, w_iin_b, w_iout_b, biascat);

    // 1. qkv1 = x @ r_in_w^T + b (1536 blocks; 8 rows x band-6 per XCD)
    gemm128s<<<1536, 256, 0, stream>>>(xb, ND, w_rin_b, ND, r_in_b, qkv1b, 3 * ND, ND, 24, 6);
    // 2. MHA-1
    attn_mfma<128><<<dim3(8, 8, 8), 256, 0, stream>>>(qkv1b, 3 * ND, ND, 2 * ND, 0.088388347648318447f);
    // 3. context (128x128 tile, 512 blocks; 8 rows x band-8 per XCD)
    gemm128s<<<512, 256, 0, stream>>>(qkv1b, 3 * ND, w_rout_b, ND, r_out_b, contextb, ND, ND, 8, 8);
    // 4. fused affinity+patterns (split epilogue, 512 blocks)
    gemm128e<<<dim3(512, 1, 1), 256, 0, stream>>>(
        contextb, 0, ND, w_aff_b, 0, ND, biascat, nullptr, 0, 0,
        affin, 0, NIN, acts0b, 0, NIN, acts0, NIN, ND, 8, 2);
    // 5. routing
    maxpart_aff_kernel<<<dim3(32, NB), 256, 0, stream>>>(affin, part_aff);
    rank_input_kernel<<<NB, 256, 0, stream>>>(part_aff, idx_in, w_sel);
    // 6. qkv2 (128x128 tile, 384 blocks; 8 rows x band-6 per XCD)
    gemm128s<<<384, 256, 0, stream>>>(acts0b, NIN, w_iin_b, NIN, i_in_b, qkv2b, 3 * NIN, NIN, 6, 6);
    // 7. MHA-2
    attn_mfma<64><<<dim3(8, 4, 8), 256, 0, stream>>>(qkv2b, 3 * NIN, NIN, 2 * NIN, 0.125f);
    // 8. attn2 out-proj -> bf16 (256 blocks)
    gemm128e<<<dim3(256, 1, 1), 256, 0, stream>>>(
        qkv2b, 0, 3 * NIN, w_iout_b, 0, NIN, i_out_b, nullptr, 0, 0,
        nullptr, 0, 0, attn2projb, 0, NIN, nullptr, 0, NIN, 4, 0);
    // 9. LN + routed gather (wave-per-row, 2048 blocks)
    ln_gather_kernel<<<2048, 256, 0, stream>>>(acts0, attn2projb, ln_g, ln_b,
                                               idx_in, w_sel, sel_actsb);
    gather_sel_cw_b<<<2048, 256, 0, stream>>>(comb_w, idx_in, sel_cwb);
    // 10. proc_acts -> bf16 (batched, 64 x 8)
    gemm128e<<<dim3(64, 1, NB), 256, 0, stream>>>(
        sel_actsb, (long)NS * KIN, KIN, sel_cwb, (long)NPROC * KIN, KIN,
        nullptr, nullptr, 0, 0,
        nullptr, 0, 0, proc_actsb, (long)NS * NPROC, NPROC, nullptr, 0, KIN, 8, 1);
    // 11. final scores + top-256
    maxpart_kernel<<<dim3(32, NB), 512, 0, stream>>>(proc_actsb, maxpart);
    rel1_kernel<<<NB, 512, 0, stream>>>(idx_in, a1w, a1b, rel1g);
    finals_kernel<<<dim3(8, NB), 256, 0, stream>>>(maxpart, rel1g, a2w, a2b, finals);
    rank_proc_kernel<<<NB, 512, 0, stream>>>(finals, pidx);
    // 12. output gathers + GEMM + residual (batched, 128 x 8)
    gather_sel_proc_b<<<dim3(NS, NB), KPROC, 0, stream>>>(proc_actsb, pidx, sel_procb);
    gather_sel_projT<<<1024, 256, 0, stream>>>(out_proj_w, pidx, sel_projT);
    gemm128e<<<dim3(128, 1, NB), 256, 0, stream>>>(
        sel_procb, (long)NS * KPROC, KPROC, sel_projT, (long)ND * KPROC, KPROC,
        nullptr, x, (long)NS * ND, ND,
        out, (long)NS * ND, ND, nullptr, 0, 0, nullptr, 0, KPROC, 16, 0);
    (void)in_sizes; (void)n_in; (void)out_size; (void)ws_size;
}